// Round 1
// baseline (14013.016 us; speedup 1.0000x reference)
//
#include <hip/hip_runtime.h>

#define NN 10000
#define NE 200000
#define LDIM 128
#define PAD 132
#define NSTEP 10
#define LN_EPS 1e-5f

// Block geometry: 256 threads, 32 items (edges/nodes) per block,
// 8 lanes per item.  li = t&7, it = t>>3.
// Each thread owns 16 outputs, interleaved quads: j = 32*c + 4*li + cc
// (chosen so ds_read_b128 of Wbuf rows is bank-conflict-free).

#define STAGE_W_FULL(WG, NELEM)                                   \
  __syncthreads();                                                \
  for (int i_ = 0; i_ < ((NELEM) + 255) / 256; ++i_) {            \
    int f_ = (int)threadIdx.x + 256 * i_;                         \
    if (f_ < (NELEM)) Wbuf[f_] = (WG)[f_];                        \
  }                                                               \
  __syncthreads();

#define STAGE_W_CHUNK(WG, ROW0)                                   \
  __syncthreads();                                                \
  for (int i_ = 0; i_ < 16; ++i_) {                               \
    int f_ = (int)threadIdx.x + 256 * i_;                         \
    Wbuf[f_] = (WG)[(ROW0) * LDIM + f_];                          \
  }                                                               \
  __syncthreads();

#define KLOOP_S(INBUF, STRIDE, KOFF, NK, ACC)                     \
  for (int kk_ = 0; kk_ < (NK); ++kk_) {                          \
    float xv_ = (INBUF)[it * (STRIDE) + (KOFF) + kk_];            \
    const float* wr_ = &Wbuf[kk_ * LDIM + 4 * li];                \
    _Pragma("unroll")                                             \
    for (int c_ = 0; c_ < 4; ++c_) {                              \
      float4 wv_ = *(const float4*)&wr_[32 * c_];                 \
      ACC[c_ * 4 + 0] = fmaf(xv_, wv_.x, ACC[c_ * 4 + 0]);        \
      ACC[c_ * 4 + 1] = fmaf(xv_, wv_.y, ACC[c_ * 4 + 1]);        \
      ACC[c_ * 4 + 2] = fmaf(xv_, wv_.z, ACC[c_ * 4 + 2]);        \
      ACC[c_ * 4 + 3] = fmaf(xv_, wv_.w, ACC[c_ * 4 + 3]);        \
    }                                                             \
  }

#define LOAD_BIAS(BG, ACC)                                        \
  _Pragma("unroll")                                               \
  for (int c_ = 0; c_ < 4; ++c_) {                                \
    float4 bv_ = *(const float4*)&(BG)[32 * c_ + 4 * li];         \
    ACC[c_ * 4 + 0] = bv_.x; ACC[c_ * 4 + 1] = bv_.y;             \
    ACC[c_ * 4 + 2] = bv_.z; ACC[c_ * 4 + 3] = bv_.w;             \
  }

#define RELU_TO_BUF(ACC, BUF)                                     \
  __syncthreads();                                                \
  _Pragma("unroll")                                               \
  for (int c_ = 0; c_ < 4; ++c_) {                                \
    float4 hv_;                                                   \
    hv_.x = fmaxf(ACC[c_ * 4 + 0], 0.f);                          \
    hv_.y = fmaxf(ACC[c_ * 4 + 1], 0.f);                          \
    hv_.z = fmaxf(ACC[c_ * 4 + 2], 0.f);                          \
    hv_.w = fmaxf(ACC[c_ * 4 + 3], 0.f);                          \
    *(float4*)&(BUF)[it * PAD + 32 * c_ + 4 * li] = hv_;          \
  }                                                               \
  __syncthreads();

#define LAYER128(WG, BG, INBUF, ACC)                              \
  LOAD_BIAS(BG, ACC)                                              \
  for (int kc_ = 0; kc_ < 4; ++kc_) {                             \
    STAGE_W_CHUNK(WG, kc_ * 32)                                   \
    KLOOP_S(INBUF, PAD, kc_ * 32, 32, ACC)                        \
  }

#define LN_STATS(ACC, MEAN, RSTD)                                 \
  float sum_ = 0.f;                                               \
  _Pragma("unroll") for (int i_ = 0; i_ < 16; ++i_) sum_ += ACC[i_]; \
  sum_ += __shfl_xor(sum_, 1);                                    \
  sum_ += __shfl_xor(sum_, 2);                                    \
  sum_ += __shfl_xor(sum_, 4);                                    \
  float MEAN = sum_ * (1.f / 128.f);                              \
  float vs_ = 0.f;                                                \
  _Pragma("unroll") for (int i_ = 0; i_ < 16; ++i_) {             \
    float d_ = ACC[i_] - MEAN; vs_ = fmaf(d_, d_, vs_);           \
  }                                                               \
  vs_ += __shfl_xor(vs_, 1);                                      \
  vs_ += __shfl_xor(vs_, 2);                                      \
  vs_ += __shfl_xor(vs_, 4);                                      \
  float RSTD = rsqrtf(vs_ * (1.f / 128.f) + LN_EPS);

// ---------------- node encoder: concat(29) -> 128 -> 128 -> 128, LN --------
__global__ __launch_bounds__(256)
void k_encode_nodes(const float* __restrict__ vel_hist, const float* __restrict__ vel_mag,
                    const float* __restrict__ bnd, const float* __restrict__ force,
                    const float* __restrict__ W0, const float* __restrict__ b0,
                    const float* __restrict__ W1, const float* __restrict__ b1,
                    const float* __restrict__ W2, const float* __restrict__ b2,
                    const float* __restrict__ lns, const float* __restrict__ lno,
                    float* __restrict__ nodes) {
  __shared__ __align__(16) float bufX[32 * PAD];
  __shared__ __align__(16) float bufH[32 * PAD];
  __shared__ __align__(16) float Wbuf[32 * LDIM];
  __shared__ float xd[32 * 32];
  const int t = threadIdx.x, li = t & 7, it = t >> 3;
  const int n0 = blockIdx.x * 32;

  for (int i = 0; i < 4; ++i) {
    int f = t + 256 * i;           // 0..1023 = 32 nodes x 32 padded dims
    int n_ = f >> 5, k = f & 31;
    int ng = n0 + n_;
    float v = 0.f;
    if (ng < NN) {
      if (k < 15)      v = vel_hist[ng * 15 + k];
      else if (k < 20) v = vel_mag[ng * 5 + (k - 15)];
      else if (k < 26) v = bnd[ng * 6 + (k - 20)];
      else if (k < 29) v = force[ng * 3 + (k - 26)];
    }
    xd[n_ * 32 + k] = v;
  }

  float acc[16];
  LOAD_BIAS(b0, acc)
  STAGE_W_FULL(W0, 29 * LDIM)      // leading barrier also covers xd staging
  KLOOP_S(xd, 32, 0, 29, acc)
  RELU_TO_BUF(acc, bufH)
  LAYER128(W1, b1, bufH, acc)
  RELU_TO_BUF(acc, bufX)
  LAYER128(W2, b2, bufX, acc)
  LN_STATS(acc, mean, rstd)

  int ng = n0 + it;
  if (ng < NN) {
#pragma unroll
    for (int c = 0; c < 4; ++c) {
      int j = 32 * c + 4 * li;
      float4 sv = *(const float4*)&lns[j];
      float4 ov = *(const float4*)&lno[j];
      float4 o;
      o.x = (acc[c * 4 + 0] - mean) * rstd * sv.x + ov.x;
      o.y = (acc[c * 4 + 1] - mean) * rstd * sv.y + ov.y;
      o.z = (acc[c * 4 + 2] - mean) * rstd * sv.z + ov.z;
      o.w = (acc[c * 4 + 3] - mean) * rstd * sv.w + ov.w;
      *(float4*)&nodes[(size_t)ng * LDIM + j] = o;
    }
  }
}

// ---------------- edge encoder: concat(4) -> 128 -> 128 -> 128, LN ---------
__global__ __launch_bounds__(256)
void k_encode_edges(const float* __restrict__ rel_disp, const float* __restrict__ rel_dist,
                    const float* __restrict__ W0, const float* __restrict__ b0,
                    const float* __restrict__ W1, const float* __restrict__ b1,
                    const float* __restrict__ W2, const float* __restrict__ b2,
                    const float* __restrict__ lns, const float* __restrict__ lno,
                    float* __restrict__ edges) {
  __shared__ __align__(16) float bufX[32 * PAD];
  __shared__ __align__(16) float bufH[32 * PAD];
  __shared__ __align__(16) float Wbuf[32 * LDIM];
  __shared__ float xd[32 * 4];
  const int t = threadIdx.x, li = t & 7, it = t >> 3;
  const int e0 = blockIdx.x * 32;

  if (t < 128) {
    int e_ = t >> 2, k = t & 3;
    int eg = e0 + e_;
    xd[t] = (k < 3) ? rel_disp[(size_t)eg * 3 + k] : rel_dist[eg];
  }

  float acc[16];
  LOAD_BIAS(b0, acc)
  STAGE_W_FULL(W0, 4 * LDIM)
  KLOOP_S(xd, 4, 0, 4, acc)
  RELU_TO_BUF(acc, bufH)
  LAYER128(W1, b1, bufH, acc)
  RELU_TO_BUF(acc, bufX)
  LAYER128(W2, b2, bufX, acc)
  LN_STATS(acc, mean, rstd)

  int eg = e0 + it;
#pragma unroll
  for (int c = 0; c < 4; ++c) {
    int j = 32 * c + 4 * li;
    float4 sv = *(const float4*)&lns[j];
    float4 ov = *(const float4*)&lno[j];
    float4 o;
    o.x = (acc[c * 4 + 0] - mean) * rstd * sv.x + ov.x;
    o.y = (acc[c * 4 + 1] - mean) * rstd * sv.y + ov.y;
    o.z = (acc[c * 4 + 2] - mean) * rstd * sv.z + ov.z;
    o.w = (acc[c * 4 + 3] - mean) * rstd * sv.w + ov.w;
    *(float4*)&edges[(size_t)eg * LDIM + j] = o;
  }
}

// -------- processor edge block: [nd[s],nd[r],ed](384) -> MLP -> LN;
//          ed += e_new (in place); aggr[rcv] += e_new (atomics) -------------
__global__ __launch_bounds__(256)
void k_proc_edge(const float* __restrict__ nodes, float* __restrict__ edges,
                 float* __restrict__ aggr,
                 const int* __restrict__ senders, const int* __restrict__ receivers,
                 const float* __restrict__ W0, const float* __restrict__ b0,
                 const float* __restrict__ W1, const float* __restrict__ b1,
                 const float* __restrict__ W2, const float* __restrict__ b2,
                 const float* __restrict__ lns, const float* __restrict__ lno) {
  __shared__ __align__(16) float bufX[32 * PAD];
  __shared__ __align__(16) float bufH[32 * PAD];
  __shared__ __align__(16) float Wbuf[32 * LDIM];
  __shared__ int sidx[32], ridx[32];
  const int t = threadIdx.x, li = t & 7, it = t >> 3;
  const int e0 = blockIdx.x * 32;

  if (t < 32) sidx[t] = senders[e0 + t];
  else if (t < 64) ridx[t - 32] = receivers[e0 + t - 32];
  __syncthreads();

  float acc[16];
  LOAD_BIAS(b0, acc)
  for (int seg = 0; seg < 3; ++seg) {
    __syncthreads();               // prior readers of bufX done
    for (int i = 0; i < 16; ++i) {
      int f = t + 256 * i;         // 32 edges x 128
      int e_ = f >> 7, k = f & 127;
      float v;
      if (seg == 0)      v = nodes[(size_t)sidx[e_] * LDIM + k];
      else if (seg == 1) v = nodes[(size_t)ridx[e_] * LDIM + k];
      else               v = edges[(size_t)(e0 + e_) * LDIM + k];
      bufX[e_ * PAD + k] = v;
    }
    __syncthreads();
    for (int kc = 0; kc < 4; ++kc) {
      STAGE_W_CHUNK(W0, seg * 128 + kc * 32)
      KLOOP_S(bufX, PAD, kc * 32, 32, acc)
    }
  }
  RELU_TO_BUF(acc, bufH)
  LAYER128(W1, b1, bufH, acc)
  RELU_TO_BUF(acc, bufX)
  LAYER128(W2, b2, bufX, acc)
  LN_STATS(acc, mean, rstd)

  const int eg = e0 + it;
  const int rr = ridx[it];
#pragma unroll
  for (int c = 0; c < 4; ++c) {
    int j = 32 * c + 4 * li;
    float4 sv = *(const float4*)&lns[j];
    float4 ov = *(const float4*)&lno[j];
    float o0 = (acc[c * 4 + 0] - mean) * rstd * sv.x + ov.x;
    float o1 = (acc[c * 4 + 1] - mean) * rstd * sv.y + ov.y;
    float o2 = (acc[c * 4 + 2] - mean) * rstd * sv.z + ov.z;
    float o3 = (acc[c * 4 + 3] - mean) * rstd * sv.w + ov.w;
    float4 old = *(const float4*)&edges[(size_t)eg * LDIM + j];
    float4 nw;
    nw.x = old.x + o0; nw.y = old.y + o1; nw.z = old.z + o2; nw.w = old.w + o3;
    *(float4*)&edges[(size_t)eg * LDIM + j] = nw;
    atomicAdd(&aggr[(size_t)rr * LDIM + j + 0], o0);
    atomicAdd(&aggr[(size_t)rr * LDIM + j + 1], o1);
    atomicAdd(&aggr[(size_t)rr * LDIM + j + 2], o2);
    atomicAdd(&aggr[(size_t)rr * LDIM + j + 3], o3);
  }
}

// -------- processor node block: [nd, aggr](256) -> MLP -> LN; nd += n_new --
__global__ __launch_bounds__(256)
void k_proc_node(float* __restrict__ nodes, const float* __restrict__ aggr,
                 const float* __restrict__ W0, const float* __restrict__ b0,
                 const float* __restrict__ W1, const float* __restrict__ b1,
                 const float* __restrict__ W2, const float* __restrict__ b2,
                 const float* __restrict__ lns, const float* __restrict__ lno) {
  __shared__ __align__(16) float bufX[32 * PAD];
  __shared__ __align__(16) float bufH[32 * PAD];
  __shared__ __align__(16) float Wbuf[32 * LDIM];
  const int t = threadIdx.x, li = t & 7, it = t >> 3;
  const int n0 = blockIdx.x * 32;

  float acc[16];
  LOAD_BIAS(b0, acc)
  for (int seg = 0; seg < 2; ++seg) {
    __syncthreads();
    const float* src = seg ? aggr : nodes;
    for (int i = 0; i < 16; ++i) {
      int f = t + 256 * i;
      int n_ = f >> 7, k = f & 127;
      int ng = n0 + n_;
      bufX[n_ * PAD + k] = (ng < NN) ? src[(size_t)ng * LDIM + k] : 0.f;
    }
    __syncthreads();
    for (int kc = 0; kc < 4; ++kc) {
      STAGE_W_CHUNK(W0, seg * 128 + kc * 32)
      KLOOP_S(bufX, PAD, kc * 32, 32, acc)
    }
  }
  RELU_TO_BUF(acc, bufH)
  LAYER128(W1, b1, bufH, acc)
  RELU_TO_BUF(acc, bufX)
  LAYER128(W2, b2, bufX, acc)
  LN_STATS(acc, mean, rstd)

  int ng = n0 + it;
  if (ng < NN) {
#pragma unroll
    for (int c = 0; c < 4; ++c) {
      int j = 32 * c + 4 * li;
      float4 sv = *(const float4*)&lns[j];
      float4 ov = *(const float4*)&lno[j];
      float o0 = (acc[c * 4 + 0] - mean) * rstd * sv.x + ov.x;
      float o1 = (acc[c * 4 + 1] - mean) * rstd * sv.y + ov.y;
      float o2 = (acc[c * 4 + 2] - mean) * rstd * sv.z + ov.z;
      float o3 = (acc[c * 4 + 3] - mean) * rstd * sv.w + ov.w;
      float4 old = *(const float4*)&nodes[(size_t)ng * LDIM + j];
      float4 nw;
      nw.x = old.x + o0; nw.y = old.y + o1; nw.z = old.z + o2; nw.w = old.w + o3;
      *(float4*)&nodes[(size_t)ng * LDIM + j] = nw;
    }
  }
}

// ---------------- decoder: 128 -> 128 -> 128 -> 3 (no LN) ------------------
__global__ __launch_bounds__(256)
void k_decode(const float* __restrict__ nodes,
              const float* __restrict__ W0, const float* __restrict__ b0,
              const float* __restrict__ W1, const float* __restrict__ b1,
              const float* __restrict__ W2, const float* __restrict__ b2,
              float* __restrict__ out) {
  __shared__ __align__(16) float bufX[32 * PAD];
  __shared__ __align__(16) float bufH[32 * PAD];
  __shared__ __align__(16) float Wbuf[32 * LDIM];
  const int t = threadIdx.x, li = t & 7, it = t >> 3;
  const int n0 = blockIdx.x * 32;

  for (int i = 0; i < 16; ++i) {
    int f = t + 256 * i;
    int n_ = f >> 7, k = f & 127;
    int ng = n0 + n_;
    bufX[n_ * PAD + k] = (ng < NN) ? nodes[(size_t)ng * LDIM + k] : 0.f;
  }

  float acc[16];
  LAYER128(W0, b0, bufX, acc)      // leading barrier covers bufX staging
  RELU_TO_BUF(acc, bufH)
  LAYER128(W1, b1, bufH, acc)
  RELU_TO_BUF(acc, bufX)

  int ng = n0 + it;
  if (li < 3 && ng < NN) {
    float o = b2[li];
    for (int k = 0; k < 128; ++k)
      o = fmaf(bufX[it * PAD + k], W2[k * 3 + li], o);
    out[(size_t)ng * 3 + li] = o;
  }
}

extern "C" void kernel_launch(void* const* d_in, const int* in_sizes, int n_in,
                              void* d_out, int out_size, void* d_ws, size_t ws_size,
                              hipStream_t stream) {
  const float* vel_hist = (const float*)d_in[0];
  const float* vel_mag  = (const float*)d_in[1];
  const float* bnd      = (const float*)d_in[2];
  const float* force    = (const float*)d_in[3];
  const float* rel_disp = (const float*)d_in[4];
  const float* rel_dist = (const float*)d_in[5];
  const int*   senders   = (const int*)d_in[6];
  const int*   receivers = (const int*)d_in[7];
  const float* en_W0 = (const float*)d_in[8];  const float* en_b0 = (const float*)d_in[9];
  const float* en_W1 = (const float*)d_in[10]; const float* en_b1 = (const float*)d_in[11];
  const float* en_W2 = (const float*)d_in[12]; const float* en_b2 = (const float*)d_in[13];
  const float* ee_W0 = (const float*)d_in[14]; const float* ee_b0 = (const float*)d_in[15];
  const float* ee_W1 = (const float*)d_in[16]; const float* ee_b1 = (const float*)d_in[17];
  const float* ee_W2 = (const float*)d_in[18]; const float* ee_b2 = (const float*)d_in[19];
  const float* pe_W0 = (const float*)d_in[20]; const float* pe_b0 = (const float*)d_in[21];
  const float* pe_W1 = (const float*)d_in[22]; const float* pe_b1 = (const float*)d_in[23];
  const float* pe_W2 = (const float*)d_in[24]; const float* pe_b2 = (const float*)d_in[25];
  const float* pn_W0 = (const float*)d_in[26]; const float* pn_b0 = (const float*)d_in[27];
  const float* pn_W1 = (const float*)d_in[28]; const float* pn_b1 = (const float*)d_in[29];
  const float* pn_W2 = (const float*)d_in[30]; const float* pn_b2 = (const float*)d_in[31];
  const float* de_W0 = (const float*)d_in[32]; const float* de_b0 = (const float*)d_in[33];
  const float* de_W1 = (const float*)d_in[34]; const float* de_b1 = (const float*)d_in[35];
  const float* de_W2 = (const float*)d_in[36]; const float* de_b2 = (const float*)d_in[37];
  const float* en_s = (const float*)d_in[38]; const float* en_o = (const float*)d_in[39];
  const float* ee_s = (const float*)d_in[40]; const float* ee_o = (const float*)d_in[41];
  const float* pe_s = (const float*)d_in[42]; const float* pe_o = (const float*)d_in[43];
  const float* pn_s = (const float*)d_in[44]; const float* pn_o = (const float*)d_in[45];

  float* ws    = (float*)d_ws;
  float* nodes = ws;                               // NN*128
  float* edges = nodes + (size_t)NN * LDIM;        // NE*128
  float* aggr  = edges + (size_t)NE * LDIM;        // NN*128

  const int nodeBlocks = (NN + 31) / 32;           // 313
  const int edgeBlocks = NE / 32;                  // 6250

  k_encode_nodes<<<nodeBlocks, 256, 0, stream>>>(
      vel_hist, vel_mag, bnd, force,
      en_W0, en_b0, en_W1, en_b1, en_W2, en_b2, en_s, en_o, nodes);
  k_encode_edges<<<edgeBlocks, 256, 0, stream>>>(
      rel_disp, rel_dist,
      ee_W0, ee_b0, ee_W1, ee_b1, ee_W2, ee_b2, ee_s, ee_o, edges);

  for (int s = 0; s < NSTEP; ++s) {
    hipMemsetAsync(aggr, 0, (size_t)NN * LDIM * sizeof(float), stream);
    k_proc_edge<<<edgeBlocks, 256, 0, stream>>>(
        nodes, edges, aggr, senders, receivers,
        pe_W0 + (size_t)s * 384 * LDIM, pe_b0 + (size_t)s * LDIM,
        pe_W1 + (size_t)s * LDIM * LDIM, pe_b1 + (size_t)s * LDIM,
        pe_W2 + (size_t)s * LDIM * LDIM, pe_b2 + (size_t)s * LDIM,
        pe_s + (size_t)s * LDIM, pe_o + (size_t)s * LDIM);
    k_proc_node<<<nodeBlocks, 256, 0, stream>>>(
        nodes, aggr,
        pn_W0 + (size_t)s * 256 * LDIM, pn_b0 + (size_t)s * LDIM,
        pn_W1 + (size_t)s * LDIM * LDIM, pn_b1 + (size_t)s * LDIM,
        pn_W2 + (size_t)s * LDIM * LDIM, pn_b2 + (size_t)s * LDIM,
        pn_s + (size_t)s * LDIM, pn_o + (size_t)s * LDIM);
  }

  k_decode<<<nodeBlocks, 256, 0, stream>>>(
      nodes, de_W0, de_b0, de_W1, de_b1, de_W2, de_b2, (float*)d_out);
}

// Round 2
// 2222.144 us; speedup vs baseline: 6.3061x; 6.3061x over previous
//
#include <hip/hip_runtime.h>

#define NN 10000
#define NE 200000
#define LDIM 128
#define PADB 136   // bf16 elements per LDS row (128 + 8): uniform bank slots for b128
#define NSTEP 10
#define LN_EPS 1e-5f

typedef unsigned short ushort_t;
typedef __attribute__((ext_vector_type(8))) short short8;
typedef __attribute__((ext_vector_type(4))) float f32x4;

#define MFMA16(a, b, c) __builtin_amdgcn_mfma_f32_16x16x32_bf16(a, b, c, 0, 0, 0)

__device__ __forceinline__ ushort_t f2bf(float f) {
  unsigned int u = __float_as_uint(f);
  return (ushort_t)((u + 0x7FFFu + ((u >> 16) & 1u)) >> 16);
}
__device__ __forceinline__ float bf2f(ushort_t h) {
  return __uint_as_float(((unsigned int)h) << 16);
}

// ---- shared-macro context: each kernel declares t, lr, kg, rw, Abuf, Wbuf, acc ----

// Stage Wbuf[128][0..127] = WT[n][K0..K0+127], WT row length KTOT. 256 threads.
#define STAGE_WT(WT, KTOT, K0)                                              \
  {                                                                         \
    const ushort_t* src_ = (WT) + (size_t)(t >> 1) * (KTOT) + (K0) + (t & 1) * 64; \
    ushort_t* dst_ = &Wbuf[(t >> 1) * PADB + (t & 1) * 64];                 \
    _Pragma("unroll")                                                       \
    for (int q_ = 0; q_ < 8; ++q_)                                          \
      *(uint4*)(dst_ + q_ * 8) = *(const uint4*)(src_ + q_ * 8);            \
  }

// acc[mt][nt] covers rows rw+16*mt+(lane>>4)*4+i, cols nt*16+(lane&15)
#define INIT_ACC(BG)                                                        \
  _Pragma("unroll")                                                         \
  for (int nt_ = 0; nt_ < 8; ++nt_) {                                       \
    float bv_ = (BG)[nt_ * 16 + lr];                                        \
    acc[0][nt_] = (f32x4){bv_, bv_, bv_, bv_};                              \
    acc[1][nt_] = acc[0][nt_];                                              \
  }

#define MFMA_K128()                                                         \
  _Pragma("unroll")                                                         \
  for (int ks_ = 0; ks_ < 4; ++ks_) {                                       \
    short8 a0_ = *(const short8*)&Abuf[(rw + lr) * PADB + ks_ * 32 + kg * 8];        \
    short8 a1_ = *(const short8*)&Abuf[(rw + 16 + lr) * PADB + ks_ * 32 + kg * 8];   \
    _Pragma("unroll")                                                       \
    for (int nt_ = 0; nt_ < 8; ++nt_) {                                     \
      short8 b_ = *(const short8*)&Wbuf[(nt_ * 16 + lr) * PADB + ks_ * 32 + kg * 8]; \
      acc[0][nt_] = MFMA16(a0_, b_, acc[0][nt_]);                           \
      acc[1][nt_] = MFMA16(a1_, b_, acc[1][nt_]);                           \
    }                                                                       \
  }

#define RELU_TO_ABUF()                                                      \
  _Pragma("unroll")                                                         \
  for (int mt_ = 0; mt_ < 2; ++mt_) {                                       \
    _Pragma("unroll")                                                       \
    for (int nt_ = 0; nt_ < 8; ++nt_) {                                     \
      _Pragma("unroll")                                                     \
      for (int i_ = 0; i_ < 4; ++i_) {                                      \
        int row_ = rw + 16 * mt_ + kg * 4 + i_;                             \
        Abuf[row_ * PADB + nt_ * 16 + lr] = f2bf(fmaxf(acc[mt_][nt_][i_], 0.f)); \
      }                                                                     \
    }                                                                       \
  }

#define LN_STATS2(MARR, RARR)                                               \
  float MARR[2][4], RARR[2][4];                                             \
  _Pragma("unroll")                                                         \
  for (int mt_ = 0; mt_ < 2; ++mt_) {                                       \
    _Pragma("unroll")                                                       \
    for (int i_ = 0; i_ < 4; ++i_) {                                        \
      float s_ = 0.f;                                                       \
      _Pragma("unroll")                                                     \
      for (int nt_ = 0; nt_ < 8; ++nt_) s_ += acc[mt_][nt_][i_];            \
      s_ += __shfl_xor(s_, 1); s_ += __shfl_xor(s_, 2);                     \
      s_ += __shfl_xor(s_, 4); s_ += __shfl_xor(s_, 8);                     \
      float m_ = s_ * (1.f / 128.f);                                        \
      float v_ = 0.f;                                                       \
      _Pragma("unroll")                                                     \
      for (int nt_ = 0; nt_ < 8; ++nt_) {                                   \
        float d_ = acc[mt_][nt_][i_] - m_; v_ = fmaf(d_, d_, v_);           \
      }                                                                     \
      v_ += __shfl_xor(v_, 1); v_ += __shfl_xor(v_, 2);                     \
      v_ += __shfl_xor(v_, 4); v_ += __shfl_xor(v_, 8);                     \
      MARR[mt_][i_] = m_;                                                   \
      RARR[mt_][i_] = rsqrtf(v_ * (1.f / 128.f) + LN_EPS);                  \
    }                                                                       \
  }

// ---- weight prep: src fp32 [steps][Ksrc][N] -> dst bf16 [steps][N][Kdst] (zero-pad k) ----
__global__ void k_prep_w(const float* __restrict__ src, ushort_t* __restrict__ dst,
                         int Ksrc, int Kdst, int N, int steps) {
  const size_t total = (size_t)steps * N * Kdst;
  for (size_t idx = (size_t)blockIdx.x * blockDim.x + threadIdx.x; idx < total;
       idx += (size_t)gridDim.x * blockDim.x) {
    int k = (int)(idx % Kdst);
    size_t tmp = idx / Kdst;
    int n = (int)(tmp % N);
    int s = (int)(tmp / N);
    float v = (k < Ksrc) ? src[((size_t)s * Ksrc + k) * N + n] : 0.f;
    dst[idx] = f2bf(v);
  }
}

// ---- node encoder: concat(29)->128->128->128, LN; writes nodes_f + nodes_bf ----
__global__ __launch_bounds__(256, 2)
void k_enc_node_m(const float* __restrict__ vh, const float* __restrict__ vm,
                  const float* __restrict__ bd, const float* __restrict__ fc,
                  const ushort_t* __restrict__ Wt0, const float* __restrict__ b0,
                  const ushort_t* __restrict__ Wt1, const float* __restrict__ b1,
                  const ushort_t* __restrict__ Wt2, const float* __restrict__ b2,
                  const float* __restrict__ lns, const float* __restrict__ lno,
                  float* __restrict__ nodes_f, ushort_t* __restrict__ nodes_bf) {
  __shared__ ushort_t Abuf[128 * PADB];
  __shared__ ushort_t Wbuf[128 * PADB];
  const int t = threadIdx.x;
  const int lane = t & 63, wid = t >> 6;
  const int lr = lane & 15, kg = lane >> 4;
  const int rw = wid * 32;
  const int n0 = blockIdx.x * 128;

  for (int idx = t; idx < 128 * 32; idx += 256) {
    int r = idx >> 5, k = idx & 31;
    int ng = n0 + r;
    float v = 0.f;
    if (ng < NN) {
      if (k < 15)      v = vh[(size_t)ng * 15 + k];
      else if (k < 20) v = vm[(size_t)ng * 5 + (k - 15)];
      else if (k < 26) v = bd[(size_t)ng * 6 + (k - 20)];
      else if (k < 29) v = fc[(size_t)ng * 3 + (k - 26)];
    }
    Abuf[r * PADB + k] = f2bf(v);
  }
  {  // Wt0: [128][32]
    const ushort_t* src = Wt0 + (t >> 1) * 32 + (t & 1) * 16;
    ushort_t* dst = &Wbuf[(t >> 1) * PADB + (t & 1) * 16];
    *(uint4*)dst = *(const uint4*)src;
    *(uint4*)(dst + 8) = *(const uint4*)(src + 8);
  }
  f32x4 acc[2][8];
  INIT_ACC(b0)
  __syncthreads();
  {  // single K=32 step
    short8 a0_ = *(const short8*)&Abuf[(rw + lr) * PADB + kg * 8];
    short8 a1_ = *(const short8*)&Abuf[(rw + 16 + lr) * PADB + kg * 8];
#pragma unroll
    for (int nt_ = 0; nt_ < 8; ++nt_) {
      short8 b_ = *(const short8*)&Wbuf[(nt_ * 16 + lr) * PADB + kg * 8];
      acc[0][nt_] = MFMA16(a0_, b_, acc[0][nt_]);
      acc[1][nt_] = MFMA16(a1_, b_, acc[1][nt_]);
    }
  }
  __syncthreads();
  RELU_TO_ABUF()
  INIT_ACC(b1)
  STAGE_WT(Wt1, 128, 0)
  __syncthreads();
  MFMA_K128()
  __syncthreads();
  RELU_TO_ABUF()
  INIT_ACC(b2)
  STAGE_WT(Wt2, 128, 0)
  __syncthreads();
  MFMA_K128()

  LN_STATS2(lmean, lrstd)
  float sv[8], ov[8];
#pragma unroll
  for (int nt = 0; nt < 8; ++nt) { sv[nt] = lns[nt * 16 + lr]; ov[nt] = lno[nt * 16 + lr]; }
#pragma unroll
  for (int mt = 0; mt < 2; ++mt)
#pragma unroll
    for (int i = 0; i < 4; ++i) {
      int row = rw + 16 * mt + kg * 4 + i;
      int ng = n0 + row;
      if (ng < NN) {
#pragma unroll
        for (int nt = 0; nt < 8; ++nt) {
          float o = (acc[mt][nt][i] - lmean[mt][i]) * lrstd[mt][i] * sv[nt] + ov[nt];
          size_t idx = (size_t)ng * LDIM + nt * 16 + lr;
          nodes_f[idx] = o;
          nodes_bf[idx] = f2bf(o);
        }
      }
    }
}

// ---- edge encoder: concat(4)->128->128->128, LN; writes edges_f ----
__global__ __launch_bounds__(256, 2)
void k_enc_edge_m(const float* __restrict__ rel_disp, const float* __restrict__ rel_dist,
                  const ushort_t* __restrict__ Wt0, const float* __restrict__ b0,
                  const ushort_t* __restrict__ Wt1, const float* __restrict__ b1,
                  const ushort_t* __restrict__ Wt2, const float* __restrict__ b2,
                  const float* __restrict__ lns, const float* __restrict__ lno,
                  float* __restrict__ edges_f) {
  __shared__ ushort_t Abuf[128 * PADB];
  __shared__ ushort_t Wbuf[128 * PADB];
  const int t = threadIdx.x;
  const int lane = t & 63, wid = t >> 6;
  const int lr = lane & 15, kg = lane >> 4;
  const int rw = wid * 32;
  const int e0 = blockIdx.x * 128;

  for (int idx = t; idx < 128 * 32; idx += 256) {
    int r = idx >> 5, k = idx & 31;
    int eg = e0 + r;
    float v = 0.f;
    if (eg < NE) {
      if (k < 3)       v = rel_disp[(size_t)eg * 3 + k];
      else if (k == 3) v = rel_dist[eg];
    }
    Abuf[r * PADB + k] = f2bf(v);
  }
  {
    const ushort_t* src = Wt0 + (t >> 1) * 32 + (t & 1) * 16;
    ushort_t* dst = &Wbuf[(t >> 1) * PADB + (t & 1) * 16];
    *(uint4*)dst = *(const uint4*)src;
    *(uint4*)(dst + 8) = *(const uint4*)(src + 8);
  }
  f32x4 acc[2][8];
  INIT_ACC(b0)
  __syncthreads();
  {
    short8 a0_ = *(const short8*)&Abuf[(rw + lr) * PADB + kg * 8];
    short8 a1_ = *(const short8*)&Abuf[(rw + 16 + lr) * PADB + kg * 8];
#pragma unroll
    for (int nt_ = 0; nt_ < 8; ++nt_) {
      short8 b_ = *(const short8*)&Wbuf[(nt_ * 16 + lr) * PADB + kg * 8];
      acc[0][nt_] = MFMA16(a0_, b_, acc[0][nt_]);
      acc[1][nt_] = MFMA16(a1_, b_, acc[1][nt_]);
    }
  }
  __syncthreads();
  RELU_TO_ABUF()
  INIT_ACC(b1)
  STAGE_WT(Wt1, 128, 0)
  __syncthreads();
  MFMA_K128()
  __syncthreads();
  RELU_TO_ABUF()
  INIT_ACC(b2)
  STAGE_WT(Wt2, 128, 0)
  __syncthreads();
  MFMA_K128()

  LN_STATS2(lmean, lrstd)
  float sv[8], ov[8];
#pragma unroll
  for (int nt = 0; nt < 8; ++nt) { sv[nt] = lns[nt * 16 + lr]; ov[nt] = lno[nt * 16 + lr]; }
#pragma unroll
  for (int mt = 0; mt < 2; ++mt)
#pragma unroll
    for (int i = 0; i < 4; ++i) {
      int row = rw + 16 * mt + kg * 4 + i;
      int eg = e0 + row;
      if (eg < NE) {
#pragma unroll
        for (int nt = 0; nt < 8; ++nt) {
          float o = (acc[mt][nt][i] - lmean[mt][i]) * lrstd[mt][i] * sv[nt] + ov[nt];
          edges_f[(size_t)eg * LDIM + nt * 16 + lr] = o;
        }
      }
    }
}

// ---- processor edge block: [nd[s],nd[r],ed](384)->128->128->128, LN;
//      edges_f += e_new; aggr[rcv] += e_new (fp32 atomics) ----
__global__ __launch_bounds__(256, 2)
void k_proc_edge_m(const ushort_t* __restrict__ nodes_bf, float* __restrict__ edges_f,
                   float* __restrict__ aggr,
                   const int* __restrict__ senders, const int* __restrict__ receivers,
                   const ushort_t* __restrict__ Wt0, const float* __restrict__ b0,
                   const ushort_t* __restrict__ Wt1, const float* __restrict__ b1,
                   const ushort_t* __restrict__ Wt2, const float* __restrict__ b2,
                   const float* __restrict__ lns, const float* __restrict__ lno) {
  __shared__ ushort_t Abuf[128 * PADB];
  __shared__ ushort_t Wbuf[128 * PADB];
  __shared__ int sidx[128], ridx[128];
  const int t = threadIdx.x;
  const int lane = t & 63, wid = t >> 6;
  const int lr = lane & 15, kg = lane >> 4;
  const int rw = wid * 32;
  const int e0 = blockIdx.x * 128;

  if (t < 128) sidx[t] = (e0 + t < NE) ? senders[e0 + t] : 0;
  else         ridx[t - 128] = (e0 + t - 128 < NE) ? receivers[e0 + t - 128] : 0;

  f32x4 acc[2][8];
  INIT_ACC(b0)
  __syncthreads();

  for (int seg = 0; seg < 3; ++seg) {
    if (seg) __syncthreads();
    {
      const int r = t >> 1, h = t & 1;
      ushort_t* dst = &Abuf[r * PADB + h * 64];
      if (seg < 2) {
        const int srow = (seg == 0) ? sidx[r] : ridx[r];
        const ushort_t* src = nodes_bf + (size_t)srow * LDIM + h * 64;
#pragma unroll
        for (int q = 0; q < 8; ++q)
          *(uint4*)(dst + q * 8) = *(const uint4*)(src + q * 8);
      } else {
        const int eg = e0 + r;
        if (eg < NE) {
          const float* src = edges_f + (size_t)eg * LDIM + h * 64;
#pragma unroll
          for (int q = 0; q < 16; ++q) {
            float4 fv = *(const float4*)(src + q * 4);
            ushort4 hv;
            hv.x = f2bf(fv.x); hv.y = f2bf(fv.y); hv.z = f2bf(fv.z); hv.w = f2bf(fv.w);
            *(ushort4*)(dst + q * 4) = hv;
          }
        } else {
          uint4 z; z.x = z.y = z.z = z.w = 0u;
#pragma unroll
          for (int q = 0; q < 8; ++q) *(uint4*)(dst + q * 8) = z;
        }
      }
    }
    STAGE_WT(Wt0, 384, seg * 128)
    __syncthreads();
    MFMA_K128()
  }
  __syncthreads();
  RELU_TO_ABUF()
  INIT_ACC(b1)
  STAGE_WT(Wt1, 128, 0)
  __syncthreads();
  MFMA_K128()
  __syncthreads();
  RELU_TO_ABUF()
  INIT_ACC(b2)
  STAGE_WT(Wt2, 128, 0)
  __syncthreads();
  MFMA_K128()

  LN_STATS2(lmean, lrstd)
  float sv[8], ov[8];
#pragma unroll
  for (int nt = 0; nt < 8; ++nt) { sv[nt] = lns[nt * 16 + lr]; ov[nt] = lno[nt * 16 + lr]; }
#pragma unroll
  for (int mt = 0; mt < 2; ++mt)
#pragma unroll
    for (int i = 0; i < 4; ++i) {
      const int row = rw + 16 * mt + kg * 4 + i;
      const int eg = e0 + row;
      if (eg < NE) {
        const int rr = ridx[row];
        float* ef = edges_f + (size_t)eg * LDIM + lr;
        float* ag = aggr + (size_t)rr * LDIM + lr;
#pragma unroll
        for (int nt = 0; nt < 8; ++nt) {
          float o = (acc[mt][nt][i] - lmean[mt][i]) * lrstd[mt][i] * sv[nt] + ov[nt];
          ef[nt * 16] += o;
          atomicAdd(&ag[nt * 16], o);
        }
      }
    }
}

// ---- processor node block: [nd, aggr](256)->128->128->128, LN;
//      nodes_f += n_new; nodes_bf refreshed ----
__global__ __launch_bounds__(256, 2)
void k_proc_node_m(float* __restrict__ nodes_f, ushort_t* __restrict__ nodes_bf,
                   const float* __restrict__ aggr,
                   const ushort_t* __restrict__ Wt0, const float* __restrict__ b0,
                   const ushort_t* __restrict__ Wt1, const float* __restrict__ b1,
                   const ushort_t* __restrict__ Wt2, const float* __restrict__ b2,
                   const float* __restrict__ lns, const float* __restrict__ lno) {
  __shared__ ushort_t Abuf[128 * PADB];
  __shared__ ushort_t Wbuf[128 * PADB];
  const int t = threadIdx.x;
  const int lane = t & 63, wid = t >> 6;
  const int lr = lane & 15, kg = lane >> 4;
  const int rw = wid * 32;
  const int n0 = blockIdx.x * 128;

  f32x4 acc[2][8];
  INIT_ACC(b0)

  for (int seg = 0; seg < 2; ++seg) {
    if (seg) __syncthreads();
    {
      const int r = t >> 1, h = t & 1;
      const int ng = n0 + r;
      ushort_t* dst = &Abuf[r * PADB + h * 64];
      if (ng < NN) {
        if (seg == 0) {
          const ushort_t* src = nodes_bf + (size_t)ng * LDIM + h * 64;
#pragma unroll
          for (int q = 0; q < 8; ++q)
            *(uint4*)(dst + q * 8) = *(const uint4*)(src + q * 8);
        } else {
          const float* src = aggr + (size_t)ng * LDIM + h * 64;
#pragma unroll
          for (int q = 0; q < 16; ++q) {
            float4 fv = *(const float4*)(src + q * 4);
            ushort4 hv;
            hv.x = f2bf(fv.x); hv.y = f2bf(fv.y); hv.z = f2bf(fv.z); hv.w = f2bf(fv.w);
            *(ushort4*)(dst + q * 4) = hv;
          }
        }
      } else {
        uint4 z; z.x = z.y = z.z = z.w = 0u;
#pragma unroll
        for (int q = 0; q < 8; ++q) *(uint4*)(dst + q * 8) = z;
      }
    }
    STAGE_WT(Wt0, 256, seg * 128)
    __syncthreads();
    MFMA_K128()
  }
  __syncthreads();
  RELU_TO_ABUF()
  INIT_ACC(b1)
  STAGE_WT(Wt1, 128, 0)
  __syncthreads();
  MFMA_K128()
  __syncthreads();
  RELU_TO_ABUF()
  INIT_ACC(b2)
  STAGE_WT(Wt2, 128, 0)
  __syncthreads();
  MFMA_K128()

  LN_STATS2(lmean, lrstd)
  float sv[8], ov[8];
#pragma unroll
  for (int nt = 0; nt < 8; ++nt) { sv[nt] = lns[nt * 16 + lr]; ov[nt] = lno[nt * 16 + lr]; }
#pragma unroll
  for (int mt = 0; mt < 2; ++mt)
#pragma unroll
    for (int i = 0; i < 4; ++i) {
      int row = rw + 16 * mt + kg * 4 + i;
      int ng = n0 + row;
      if (ng < NN) {
#pragma unroll
        for (int nt = 0; nt < 8; ++nt) {
          float o = (acc[mt][nt][i] - lmean[mt][i]) * lrstd[mt][i] * sv[nt] + ov[nt];
          size_t idx = (size_t)ng * LDIM + nt * 16 + lr;
          float nv = nodes_f[idx] + o;
          nodes_f[idx] = nv;
          nodes_bf[idx] = f2bf(nv);
        }
      }
    }
}

// ---- decoder: 128->128->128->3 (no LN) ----
__global__ __launch_bounds__(256, 2)
void k_dec_m(const ushort_t* __restrict__ nodes_bf,
             const ushort_t* __restrict__ Wt0, const float* __restrict__ b0,
             const ushort_t* __restrict__ Wt1, const float* __restrict__ b1,
             const float* __restrict__ W2f, const float* __restrict__ b2,
             float* __restrict__ out) {
  __shared__ ushort_t Abuf[128 * PADB];
  __shared__ ushort_t Wbuf[128 * PADB];
  const int t = threadIdx.x;
  const int lane = t & 63, wid = t >> 6;
  const int lr = lane & 15, kg = lane >> 4;
  const int rw = wid * 32;
  const int n0 = blockIdx.x * 128;

  {
    const int r = t >> 1, h = t & 1;
    const int ng = n0 + r;
    ushort_t* dst = &Abuf[r * PADB + h * 64];
    if (ng < NN) {
      const ushort_t* src = nodes_bf + (size_t)ng * LDIM + h * 64;
#pragma unroll
      for (int q = 0; q < 8; ++q)
        *(uint4*)(dst + q * 8) = *(const uint4*)(src + q * 8);
    } else {
      uint4 z; z.x = z.y = z.z = z.w = 0u;
#pragma unroll
      for (int q = 0; q < 8; ++q) *(uint4*)(dst + q * 8) = z;
    }
  }
  f32x4 acc[2][8];
  INIT_ACC(b0)
  STAGE_WT(Wt0, 128, 0)
  __syncthreads();
  MFMA_K128()
  __syncthreads();
  RELU_TO_ABUF()
  INIT_ACC(b1)
  STAGE_WT(Wt1, 128, 0)
  __syncthreads();
  MFMA_K128()
  __syncthreads();
  RELU_TO_ABUF()
  __syncthreads();

  if (t < 128) {
    const int ng = n0 + t;
    if (ng < NN) {
      float s0 = b2[0], s1 = b2[1], s2 = b2[2];
      for (int k = 0; k < 128; ++k) {
        float xv = bf2f(Abuf[t * PADB + k]);
        s0 = fmaf(xv, W2f[k * 3 + 0], s0);
        s1 = fmaf(xv, W2f[k * 3 + 1], s1);
        s2 = fmaf(xv, W2f[k * 3 + 2], s2);
      }
      out[(size_t)ng * 3 + 0] = s0;
      out[(size_t)ng * 3 + 1] = s1;
      out[(size_t)ng * 3 + 2] = s2;
    }
  }
}

extern "C" void kernel_launch(void* const* d_in, const int* in_sizes, int n_in,
                              void* d_out, int out_size, void* d_ws, size_t ws_size,
                              hipStream_t stream) {
  const float* vel_hist = (const float*)d_in[0];
  const float* vel_mag  = (const float*)d_in[1];
  const float* bnd      = (const float*)d_in[2];
  const float* force    = (const float*)d_in[3];
  const float* rel_disp = (const float*)d_in[4];
  const float* rel_dist = (const float*)d_in[5];
  const int*   senders   = (const int*)d_in[6];
  const int*   receivers = (const int*)d_in[7];
  const float* en_W0 = (const float*)d_in[8];  const float* en_b0 = (const float*)d_in[9];
  const float* en_W1 = (const float*)d_in[10]; const float* en_b1 = (const float*)d_in[11];
  const float* en_W2 = (const float*)d_in[12]; const float* en_b2 = (const float*)d_in[13];
  const float* ee_W0 = (const float*)d_in[14]; const float* ee_b0 = (const float*)d_in[15];
  const float* ee_W1 = (const float*)d_in[16]; const float* ee_b1 = (const float*)d_in[17];
  const float* ee_W2 = (const float*)d_in[18]; const float* ee_b2 = (const float*)d_in[19];
  const float* pe_W0 = (const float*)d_in[20]; const float* pe_b0 = (const float*)d_in[21];
  const float* pe_W1 = (const float*)d_in[22]; const float* pe_b1 = (const float*)d_in[23];
  const float* pe_W2 = (const float*)d_in[24]; const float* pe_b2 = (const float*)d_in[25];
  const float* pn_W0 = (const float*)d_in[26]; const float* pn_b0 = (const float*)d_in[27];
  const float* pn_W1 = (const float*)d_in[28]; const float* pn_b1 = (const float*)d_in[29];
  const float* pn_W2 = (const float*)d_in[30]; const float* pn_b2 = (const float*)d_in[31];
  const float* de_W0 = (const float*)d_in[32]; const float* de_b0 = (const float*)d_in[33];
  const float* de_W1 = (const float*)d_in[34]; const float* de_b1 = (const float*)d_in[35];
  const float* de_W2 = (const float*)d_in[36]; const float* de_b2 = (const float*)d_in[37];
  const float* en_s = (const float*)d_in[38]; const float* en_o = (const float*)d_in[39];
  const float* ee_s = (const float*)d_in[40]; const float* ee_o = (const float*)d_in[41];
  const float* pe_s = (const float*)d_in[42]; const float* pe_o = (const float*)d_in[43];
  const float* pn_s = (const float*)d_in[44]; const float* pn_o = (const float*)d_in[45];

  float* nodes_f = (float*)d_ws;
  float* edges_f = nodes_f + (size_t)NN * LDIM;
  float* aggr    = edges_f + (size_t)NE * LDIM;
  ushort_t* nodes_bf = (ushort_t*)(aggr + (size_t)NN * LDIM);
  ushort_t* w = nodes_bf + (size_t)NN * LDIM;
  ushort_t* wEn0 = w; w += 128 * 32;
  ushort_t* wEn1 = w; w += 128 * 128;
  ushort_t* wEn2 = w; w += 128 * 128;
  ushort_t* wEe0 = w; w += 128 * 32;
  ushort_t* wEe1 = w; w += 128 * 128;
  ushort_t* wEe2 = w; w += 128 * 128;
  ushort_t* wPe0 = w; w += (size_t)NSTEP * 128 * 384;
  ushort_t* wPe1 = w; w += (size_t)NSTEP * 128 * 128;
  ushort_t* wPe2 = w; w += (size_t)NSTEP * 128 * 128;
  ushort_t* wPn0 = w; w += (size_t)NSTEP * 128 * 256;
  ushort_t* wPn1 = w; w += (size_t)NSTEP * 128 * 128;
  ushort_t* wPn2 = w; w += (size_t)NSTEP * 128 * 128;
  ushort_t* wDe0 = w; w += 128 * 128;
  ushort_t* wDe1 = w; w += 128 * 128;

  auto prep = [&](const float* src, ushort_t* dst, int Ks, int Kd, int N_, int st) {
    size_t total = (size_t)st * N_ * Kd;
    int blocks = (int)((total + 255) / 256);
    if (blocks > 1024) blocks = 1024;
    k_prep_w<<<blocks, 256, 0, stream>>>(src, dst, Ks, Kd, N_, st);
  };
  prep(en_W0, wEn0, 29, 32, 128, 1);
  prep(en_W1, wEn1, 128, 128, 128, 1);
  prep(en_W2, wEn2, 128, 128, 128, 1);
  prep(ee_W0, wEe0, 4, 32, 128, 1);
  prep(ee_W1, wEe1, 128, 128, 128, 1);
  prep(ee_W2, wEe2, 128, 128, 128, 1);
  prep(pe_W0, wPe0, 384, 384, 128, NSTEP);
  prep(pe_W1, wPe1, 128, 128, 128, NSTEP);
  prep(pe_W2, wPe2, 128, 128, 128, NSTEP);
  prep(pn_W0, wPn0, 256, 256, 128, NSTEP);
  prep(pn_W1, wPn1, 128, 128, 128, NSTEP);
  prep(pn_W2, wPn2, 128, 128, 128, NSTEP);
  prep(de_W0, wDe0, 128, 128, 128, 1);
  prep(de_W1, wDe1, 128, 128, 128, 1);

  const int NB = (NN + 127) / 128;   // 79
  const int EB = (NE + 127) / 128;   // 1563

  k_enc_node_m<<<NB, 256, 0, stream>>>(vel_hist, vel_mag, bnd, force,
      wEn0, en_b0, wEn1, en_b1, wEn2, en_b2, en_s, en_o, nodes_f, nodes_bf);
  k_enc_edge_m<<<EB, 256, 0, stream>>>(rel_disp, rel_dist,
      wEe0, ee_b0, wEe1, ee_b1, wEe2, ee_b2, ee_s, ee_o, edges_f);

  for (int s = 0; s < NSTEP; ++s) {
    hipMemsetAsync(aggr, 0, (size_t)NN * LDIM * sizeof(float), stream);
    k_proc_edge_m<<<EB, 256, 0, stream>>>(nodes_bf, edges_f, aggr, senders, receivers,
        wPe0 + (size_t)s * 128 * 384, pe_b0 + (size_t)s * LDIM,
        wPe1 + (size_t)s * 128 * 128, pe_b1 + (size_t)s * LDIM,
        wPe2 + (size_t)s * 128 * 128, pe_b2 + (size_t)s * LDIM,
        pe_s + (size_t)s * LDIM, pe_o + (size_t)s * LDIM);
    k_proc_node_m<<<NB, 256, 0, stream>>>(nodes_f, nodes_bf, aggr,
        wPn0 + (size_t)s * 128 * 256, pn_b0 + (size_t)s * LDIM,
        wPn1 + (size_t)s * 128 * 128, pn_b1 + (size_t)s * LDIM,
        wPn2 + (size_t)s * 128 * 128, pn_b2 + (size_t)s * LDIM,
        pn_s + (size_t)s * LDIM, pn_o + (size_t)s * LDIM);
  }

  k_dec_m<<<NB, 256, 0, stream>>>(nodes_bf, wDe0, de_b0, wDe1, de_b1, de_W2, de_b2,
                                  (float*)d_out);
}

// Round 3
// 2027.550 us; speedup vs baseline: 6.9113x; 1.0960x over previous
//
#include <hip/hip_runtime.h>

#define NN 10000
#define NE 200000
#define LDIM 128
#define PADB 136   // bf16 elements per LDS row (128 + 8)
#define NSTEP 10
#define LN_EPS 1e-5f

typedef unsigned short ushort_t;
typedef __attribute__((ext_vector_type(8))) short short8;
typedef __attribute__((ext_vector_type(4))) float f32x4;

#define MFMA16(a, b, c) __builtin_amdgcn_mfma_f32_16x16x32_bf16(a, b, c, 0, 0, 0)

__device__ __forceinline__ ushort_t f2bf(float f) {
  unsigned int u = __float_as_uint(f);
  return (ushort_t)((u + 0x7FFFu + ((u >> 16) & 1u)) >> 16);
}
__device__ __forceinline__ float bf2f(ushort_t h) {
  return __uint_as_float(((unsigned int)h) << 16);
}

// ---- shared-macro context: kernels declare t, lr, kg, rw, Abuf, Wbuf, acc ----

#define STAGE_WT(WT, KTOT, K0)                                              \
  {                                                                         \
    const ushort_t* src_ = (WT) + (size_t)(t >> 1) * (KTOT) + (K0) + (t & 1) * 64; \
    ushort_t* dst_ = &Wbuf[(t >> 1) * PADB + (t & 1) * 64];                 \
    _Pragma("unroll")                                                       \
    for (int q_ = 0; q_ < 8; ++q_)                                          \
      *(uint4*)(dst_ + q_ * 8) = *(const uint4*)(src_ + q_ * 8);            \
  }

#define INIT_ACC(BG)                                                        \
  _Pragma("unroll")                                                         \
  for (int nt_ = 0; nt_ < 8; ++nt_) {                                       \
    float bv_ = (BG)[nt_ * 16 + lr];                                        \
    acc[0][nt_] = (f32x4){bv_, bv_, bv_, bv_};                              \
    acc[1][nt_] = acc[0][nt_];                                              \
  }

#define MFMA_K128()                                                         \
  _Pragma("unroll")                                                         \
  for (int ks_ = 0; ks_ < 4; ++ks_) {                                       \
    short8 a0_ = *(const short8*)&Abuf[(rw + lr) * PADB + ks_ * 32 + kg * 8];        \
    short8 a1_ = *(const short8*)&Abuf[(rw + 16 + lr) * PADB + ks_ * 32 + kg * 8];   \
    _Pragma("unroll")                                                       \
    for (int nt_ = 0; nt_ < 8; ++nt_) {                                     \
      short8 b_ = *(const short8*)&Wbuf[(nt_ * 16 + lr) * PADB + ks_ * 32 + kg * 8]; \
      acc[0][nt_] = MFMA16(a0_, b_, acc[0][nt_]);                           \
      acc[1][nt_] = MFMA16(a1_, b_, acc[1][nt_]);                           \
    }                                                                       \
  }

#define RELU_TO_ABUF()                                                      \
  _Pragma("unroll")                                                         \
  for (int mt_ = 0; mt_ < 2; ++mt_) {                                       \
    _Pragma("unroll")                                                       \
    for (int nt_ = 0; nt_ < 8; ++nt_) {                                     \
      _Pragma("unroll")                                                     \
      for (int i_ = 0; i_ < 4; ++i_) {                                      \
        int row_ = rw + 16 * mt_ + kg * 4 + i_;                             \
        Abuf[row_ * PADB + nt_ * 16 + lr] = f2bf(fmaxf(acc[mt_][nt_][i_], 0.f)); \
      }                                                                     \
    }                                                                       \
  }

#define LN_STATS2(MARR, RARR)                                               \
  float MARR[2][4], RARR[2][4];                                             \
  _Pragma("unroll")                                                         \
  for (int mt_ = 0; mt_ < 2; ++mt_) {                                       \
    _Pragma("unroll")                                                       \
    for (int i_ = 0; i_ < 4; ++i_) {                                        \
      float s_ = 0.f;                                                       \
      _Pragma("unroll")                                                     \
      for (int nt_ = 0; nt_ < 8; ++nt_) s_ += acc[mt_][nt_][i_];            \
      s_ += __shfl_xor(s_, 1); s_ += __shfl_xor(s_, 2);                     \
      s_ += __shfl_xor(s_, 4); s_ += __shfl_xor(s_, 8);                     \
      float m_ = s_ * (1.f / 128.f);                                        \
      float v_ = 0.f;                                                       \
      _Pragma("unroll")                                                     \
      for (int nt_ = 0; nt_ < 8; ++nt_) {                                   \
        float d_ = acc[mt_][nt_][i_] - m_; v_ = fmaf(d_, d_, v_);           \
      }                                                                     \
      v_ += __shfl_xor(v_, 1); v_ += __shfl_xor(v_, 2);                     \
      v_ += __shfl_xor(v_, 4); v_ += __shfl_xor(v_, 8);                     \
      MARR[mt_][i_] = m_;                                                   \
      RARR[mt_][i_] = rsqrtf(v_ * (1.f / 128.f) + LN_EPS);                  \
    }                                                                       \
  }

// ---- weight prep: fp32 [steps][Ksrc][N] -> bf16 [steps][N][Kdst] ----
__global__ void k_prep_w(const float* __restrict__ src, ushort_t* __restrict__ dst,
                         int Ksrc, int Kdst, int N, int steps) {
  const size_t total = (size_t)steps * N * Kdst;
  for (size_t idx = (size_t)blockIdx.x * blockDim.x + threadIdx.x; idx < total;
       idx += (size_t)gridDim.x * blockDim.x) {
    int k = (int)(idx % Kdst);
    size_t tmp = idx / Kdst;
    int n = (int)(tmp % N);
    int s = (int)(tmp / N);
    float v = (k < Ksrc) ? src[((size_t)s * Ksrc + k) * N + n] : 0.f;
    dst[idx] = f2bf(v);
  }
}

// ---- counting sort of edges by receiver ----
__global__ void k_hist(const int* __restrict__ recv, int* __restrict__ cnt) {
  int e = blockIdx.x * 256 + threadIdx.x;
  if (e < NE) atomicAdd(&cnt[recv[e]], 1);
}

__global__ __launch_bounds__(256)
void k_scan(const int* __restrict__ cnt, int* __restrict__ row_start) {
  __shared__ int part[256];
  const int t = threadIdx.x;
  const int base = t * 40;                 // 256*40 = 10240 >= NN
  int sum = 0;
  for (int i = 0; i < 40; ++i) {
    int b = base + i;
    if (b < NN) sum += cnt[b];
  }
  part[t] = sum;
  __syncthreads();
  for (int off = 1; off < 256; off <<= 1) {
    int v = part[t];
    int u = (t >= off) ? part[t - off] : 0;
    __syncthreads();
    part[t] = v + u;
    __syncthreads();
  }
  int run = (t == 0) ? 0 : part[t - 1];
  for (int i = 0; i < 40; ++i) {
    int b = base + i;
    if (b < NN) { row_start[b] = run; run += cnt[b]; }
  }
  if (t == 255) row_start[NN] = run;       // == NE
}

__global__ void k_scatter(const int* __restrict__ send, const int* __restrict__ recv,
                          const int* __restrict__ row_start, int* __restrict__ cursor,
                          int* __restrict__ esrc, int* __restrict__ sSend,
                          int* __restrict__ sRecv) {
  int e = blockIdx.x * 256 + threadIdx.x;
  if (e >= NE) return;
  int r = recv[e];
  int pos = row_start[r] + atomicAdd(&cursor[r], 1);
  esrc[pos] = e;
  sSend[pos] = send[e];
  sRecv[pos] = r;
}

// ---- node encoder: concat(29)->128->128->128, LN ----
__global__ __launch_bounds__(256, 2)
void k_enc_node_m(const float* __restrict__ vh, const float* __restrict__ vm,
                  const float* __restrict__ bd, const float* __restrict__ fc,
                  const ushort_t* __restrict__ Wt0, const float* __restrict__ b0,
                  const ushort_t* __restrict__ Wt1, const float* __restrict__ b1,
                  const ushort_t* __restrict__ Wt2, const float* __restrict__ b2,
                  const float* __restrict__ lns, const float* __restrict__ lno,
                  float* __restrict__ nodes_f, ushort_t* __restrict__ nodes_bf) {
  __shared__ ushort_t Abuf[128 * PADB];
  __shared__ ushort_t Wbuf[128 * PADB];
  const int t = threadIdx.x;
  const int lane = t & 63, wid = t >> 6;
  const int lr = lane & 15, kg = lane >> 4;
  const int rw = wid * 32;
  const int n0 = blockIdx.x * 128;

  for (int idx = t; idx < 128 * 32; idx += 256) {
    int r = idx >> 5, k = idx & 31;
    int ng = n0 + r;
    float v = 0.f;
    if (ng < NN) {
      if (k < 15)      v = vh[(size_t)ng * 15 + k];
      else if (k < 20) v = vm[(size_t)ng * 5 + (k - 15)];
      else if (k < 26) v = bd[(size_t)ng * 6 + (k - 20)];
      else if (k < 29) v = fc[(size_t)ng * 3 + (k - 26)];
    }
    Abuf[r * PADB + k] = f2bf(v);
  }
  {
    const ushort_t* src = Wt0 + (t >> 1) * 32 + (t & 1) * 16;
    ushort_t* dst = &Wbuf[(t >> 1) * PADB + (t & 1) * 16];
    *(uint4*)dst = *(const uint4*)src;
    *(uint4*)(dst + 8) = *(const uint4*)(src + 8);
  }
  f32x4 acc[2][8];
  INIT_ACC(b0)
  __syncthreads();
  {
    short8 a0_ = *(const short8*)&Abuf[(rw + lr) * PADB + kg * 8];
    short8 a1_ = *(const short8*)&Abuf[(rw + 16 + lr) * PADB + kg * 8];
#pragma unroll
    for (int nt_ = 0; nt_ < 8; ++nt_) {
      short8 b_ = *(const short8*)&Wbuf[(nt_ * 16 + lr) * PADB + kg * 8];
      acc[0][nt_] = MFMA16(a0_, b_, acc[0][nt_]);
      acc[1][nt_] = MFMA16(a1_, b_, acc[1][nt_]);
    }
  }
  __syncthreads();
  RELU_TO_ABUF()
  INIT_ACC(b1)
  STAGE_WT(Wt1, 128, 0)
  __syncthreads();
  MFMA_K128()
  __syncthreads();
  RELU_TO_ABUF()
  INIT_ACC(b2)
  STAGE_WT(Wt2, 128, 0)
  __syncthreads();
  MFMA_K128()

  LN_STATS2(lmean, lrstd)
  float sv[8], ov[8];
#pragma unroll
  for (int nt = 0; nt < 8; ++nt) { sv[nt] = lns[nt * 16 + lr]; ov[nt] = lno[nt * 16 + lr]; }
#pragma unroll
  for (int mt = 0; mt < 2; ++mt)
#pragma unroll
    for (int i = 0; i < 4; ++i) {
      int row = rw + 16 * mt + kg * 4 + i;
      int ng = n0 + row;
      if (ng < NN) {
#pragma unroll
        for (int nt = 0; nt < 8; ++nt) {
          float o = (acc[mt][nt][i] - lmean[mt][i]) * lrstd[mt][i] * sv[nt] + ov[nt];
          size_t idx = (size_t)ng * LDIM + nt * 16 + lr;
          nodes_f[idx] = o;
          nodes_bf[idx] = f2bf(o);
        }
      }
    }
}

// ---- edge encoder (sorted order, gathers via esrc) ----
__global__ __launch_bounds__(256, 2)
void k_enc_edge_m(const float* __restrict__ rel_disp, const float* __restrict__ rel_dist,
                  const int* __restrict__ esrc,
                  const ushort_t* __restrict__ Wt0, const float* __restrict__ b0,
                  const ushort_t* __restrict__ Wt1, const float* __restrict__ b1,
                  const ushort_t* __restrict__ Wt2, const float* __restrict__ b2,
                  const float* __restrict__ lns, const float* __restrict__ lno,
                  float* __restrict__ edges_f) {
  __shared__ ushort_t Abuf[128 * PADB];
  __shared__ ushort_t Wbuf[128 * PADB];
  __shared__ int eidx[128];
  const int t = threadIdx.x;
  const int lane = t & 63, wid = t >> 6;
  const int lr = lane & 15, kg = lane >> 4;
  const int rw = wid * 32;
  const int e0 = blockIdx.x * 128;

  if (t < 128) eidx[t] = (e0 + t < NE) ? esrc[e0 + t] : 0;
  __syncthreads();

  for (int idx = t; idx < 128 * 32; idx += 256) {
    int r = idx >> 5, k = idx & 31;
    float v = 0.f;
    if (e0 + r < NE) {
      int eo = eidx[r];
      if (k < 3)       v = rel_disp[(size_t)eo * 3 + k];
      else if (k == 3) v = rel_dist[eo];
    }
    Abuf[r * PADB + k] = f2bf(v);
  }
  {
    const ushort_t* src = Wt0 + (t >> 1) * 32 + (t & 1) * 16;
    ushort_t* dst = &Wbuf[(t >> 1) * PADB + (t & 1) * 16];
    *(uint4*)dst = *(const uint4*)src;
    *(uint4*)(dst + 8) = *(const uint4*)(src + 8);
  }
  f32x4 acc[2][8];
  INIT_ACC(b0)
  __syncthreads();
  {
    short8 a0_ = *(const short8*)&Abuf[(rw + lr) * PADB + kg * 8];
    short8 a1_ = *(const short8*)&Abuf[(rw + 16 + lr) * PADB + kg * 8];
#pragma unroll
    for (int nt_ = 0; nt_ < 8; ++nt_) {
      short8 b_ = *(const short8*)&Wbuf[(nt_ * 16 + lr) * PADB + kg * 8];
      acc[0][nt_] = MFMA16(a0_, b_, acc[0][nt_]);
      acc[1][nt_] = MFMA16(a1_, b_, acc[1][nt_]);
    }
  }
  __syncthreads();
  RELU_TO_ABUF()
  INIT_ACC(b1)
  STAGE_WT(Wt1, 128, 0)
  __syncthreads();
  MFMA_K128()
  __syncthreads();
  RELU_TO_ABUF()
  INIT_ACC(b2)
  STAGE_WT(Wt2, 128, 0)
  __syncthreads();
  MFMA_K128()

  LN_STATS2(lmean, lrstd)
  float sv[8], ov[8];
#pragma unroll
  for (int nt = 0; nt < 8; ++nt) { sv[nt] = lns[nt * 16 + lr]; ov[nt] = lno[nt * 16 + lr]; }
#pragma unroll
  for (int mt = 0; mt < 2; ++mt)
#pragma unroll
    for (int i = 0; i < 4; ++i) {
      int row = rw + 16 * mt + kg * 4 + i;
      int eg = e0 + row;
      if (eg < NE) {
#pragma unroll
        for (int nt = 0; nt < 8; ++nt) {
          float o = (acc[mt][nt][i] - lmean[mt][i]) * lrstd[mt][i] * sv[nt] + ov[nt];
          edges_f[(size_t)eg * LDIM + nt * 16 + lr] = o;
        }
      }
    }
}

// ---- processor edge block (sorted edges, no atomics) ----
__global__ __launch_bounds__(256, 2)
void k_proc_edge_m(const ushort_t* __restrict__ nodes_bf, float* __restrict__ edges_f,
                   ushort_t* __restrict__ enew,
                   const int* __restrict__ sSend, const int* __restrict__ sRecv,
                   const ushort_t* __restrict__ Wt0, const float* __restrict__ b0,
                   const ushort_t* __restrict__ Wt1, const float* __restrict__ b1,
                   const ushort_t* __restrict__ Wt2, const float* __restrict__ b2,
                   const float* __restrict__ lns, const float* __restrict__ lno) {
  __shared__ ushort_t smem[2 * 128 * PADB];
  __shared__ int sidx[128], ridx[128];
  ushort_t* Abuf = smem;
  ushort_t* Wbuf = smem + 128 * PADB;
  const int t = threadIdx.x;
  const int lane = t & 63, wid = t >> 6;
  const int lr = lane & 15, kg = lane >> 4;
  const int rw = wid * 32;
  const int e0 = blockIdx.x * 128;

  if (t < 128) sidx[t] = (e0 + t < NE) ? sSend[e0 + t] : 0;
  else         ridx[t - 128] = (e0 + t - 128 < NE) ? sRecv[e0 + t - 128] : 0;

  f32x4 acc[2][8];
  INIT_ACC(b0)
  __syncthreads();

  for (int seg = 0; seg < 3; ++seg) {
    if (seg) __syncthreads();
    {
      const int r = t >> 1, h = t & 1;
      ushort_t* dst = &Abuf[r * PADB + h * 64];
      if (seg < 2) {
        const int srow = (seg == 0) ? sidx[r] : ridx[r];
        const ushort_t* src = nodes_bf + (size_t)srow * LDIM + h * 64;
#pragma unroll
        for (int q = 0; q < 8; ++q)
          *(uint4*)(dst + q * 8) = *(const uint4*)(src + q * 8);
      } else {
        const int eg = e0 + r;
        if (eg < NE) {
          const float* src = edges_f + (size_t)eg * LDIM + h * 64;
#pragma unroll
          for (int q = 0; q < 16; ++q) {
            float4 fv = *(const float4*)(src + q * 4);
            ushort4 hv;
            hv.x = f2bf(fv.x); hv.y = f2bf(fv.y); hv.z = f2bf(fv.z); hv.w = f2bf(fv.w);
            *(ushort4*)(dst + q * 4) = hv;
          }
        } else {
          uint4 z; z.x = z.y = z.z = z.w = 0u;
#pragma unroll
          for (int q = 0; q < 8; ++q) *(uint4*)(dst + q * 8) = z;
        }
      }
    }
    STAGE_WT(Wt0, 384, seg * 128)
    __syncthreads();
    MFMA_K128()
  }
  __syncthreads();
  RELU_TO_ABUF()
  INIT_ACC(b1)
  STAGE_WT(Wt1, 128, 0)
  __syncthreads();
  MFMA_K128()
  __syncthreads();
  RELU_TO_ABUF()
  INIT_ACC(b2)
  STAGE_WT(Wt2, 128, 0)
  __syncthreads();
  MFMA_K128()

  LN_STATS2(lmean, lrstd)
  float sv[8], ov[8];
#pragma unroll
  for (int nt = 0; nt < 8; ++nt) { sv[nt] = lns[nt * 16 + lr]; ov[nt] = lno[nt * 16 + lr]; }

  // LN'd outputs -> LDS fp32 (stride 132), then coalesced vectorized epilogue
  float* fbuf = (float*)smem;
  __syncthreads();                         // all MFMA LDS reads done
#pragma unroll
  for (int mt = 0; mt < 2; ++mt)
#pragma unroll
    for (int i = 0; i < 4; ++i) {
      int row = rw + 16 * mt + kg * 4 + i;
#pragma unroll
      for (int nt = 0; nt < 8; ++nt)
        fbuf[row * 132 + nt * 16 + lr] =
            (acc[mt][nt][i] - lmean[mt][i]) * lrstd[mt][i] * sv[nt] + ov[nt];
    }
  __syncthreads();
  {
    const int r = t >> 1, h = t & 1;
    const int eg = e0 + r;
    if (eg < NE) {
      float* ef = edges_f + (size_t)eg * LDIM + h * 64;
      ushort_t* en = enew + (size_t)eg * LDIM + h * 64;
      const float* fb = fbuf + r * 132 + h * 64;
#pragma unroll
      for (int q = 0; q < 16; ++q) {
        float4 o4 = *(const float4*)&fb[q * 4];
        float4 e4 = *(const float4*)&ef[q * 4];
        e4.x += o4.x; e4.y += o4.y; e4.z += o4.z; e4.w += o4.w;
        *(float4*)&ef[q * 4] = e4;
        ushort4 h4;
        h4.x = f2bf(o4.x); h4.y = f2bf(o4.y); h4.z = f2bf(o4.z); h4.w = f2bf(o4.w);
        *(ushort4*)&en[q * 4] = h4;
      }
    }
  }
}

// ---- segment-sum aggregation: enew (sorted) -> aggr_bf ----
__global__ __launch_bounds__(256)
void k_aggr(const ushort_t* __restrict__ enew, const int* __restrict__ row_start,
            ushort_t* __restrict__ aggr_bf) {
  const int t = threadIdx.x;
  const int n = blockIdx.x * 4 + (t >> 6);
  const int c = (t & 63) * 2;
  if (n >= NN) return;
  const int b = row_start[n], e = row_start[n + 1];
  float s0 = 0.f, s1 = 0.f;
  for (int i = b; i < e; ++i) {
    ushort2 v = *(const ushort2*)&enew[(size_t)i * LDIM + c];
    s0 += bf2f(v.x);
    s1 += bf2f(v.y);
  }
  ushort2 o;
  o.x = f2bf(s0); o.y = f2bf(s1);
  *(ushort2*)&aggr_bf[(size_t)n * LDIM + c] = o;
}

// ---- processor node block: [nd, aggr](256)->MLP->LN; nd += n_new ----
__global__ __launch_bounds__(256, 2)
void k_proc_node_m(float* __restrict__ nodes_f, ushort_t* __restrict__ nodes_bf,
                   const ushort_t* __restrict__ aggr_bf,
                   const ushort_t* __restrict__ Wt0, const float* __restrict__ b0,
                   const ushort_t* __restrict__ Wt1, const float* __restrict__ b1,
                   const ushort_t* __restrict__ Wt2, const float* __restrict__ b2,
                   const float* __restrict__ lns, const float* __restrict__ lno) {
  __shared__ ushort_t Abuf[128 * PADB];
  __shared__ ushort_t Wbuf[128 * PADB];
  const int t = threadIdx.x;
  const int lane = t & 63, wid = t >> 6;
  const int lr = lane & 15, kg = lane >> 4;
  const int rw = wid * 32;
  const int n0 = blockIdx.x * 128;

  f32x4 acc[2][8];
  INIT_ACC(b0)

  for (int seg = 0; seg < 2; ++seg) {
    if (seg) __syncthreads();
    {
      const int r = t >> 1, h = t & 1;
      const int ng = n0 + r;
      ushort_t* dst = &Abuf[r * PADB + h * 64];
      if (ng < NN) {
        const ushort_t* src =
            (seg == 0 ? nodes_bf : aggr_bf) + (size_t)ng * LDIM + h * 64;
#pragma unroll
        for (int q = 0; q < 8; ++q)
          *(uint4*)(dst + q * 8) = *(const uint4*)(src + q * 8);
      } else {
        uint4 z; z.x = z.y = z.z = z.w = 0u;
#pragma unroll
        for (int q = 0; q < 8; ++q) *(uint4*)(dst + q * 8) = z;
      }
    }
    STAGE_WT(Wt0, 256, seg * 128)
    __syncthreads();
    MFMA_K128()
  }
  __syncthreads();
  RELU_TO_ABUF()
  INIT_ACC(b1)
  STAGE_WT(Wt1, 128, 0)
  __syncthreads();
  MFMA_K128()
  __syncthreads();
  RELU_TO_ABUF()
  INIT_ACC(b2)
  STAGE_WT(Wt2, 128, 0)
  __syncthreads();
  MFMA_K128()

  LN_STATS2(lmean, lrstd)
  float sv[8], ov[8];
#pragma unroll
  for (int nt = 0; nt < 8; ++nt) { sv[nt] = lns[nt * 16 + lr]; ov[nt] = lno[nt * 16 + lr]; }
#pragma unroll
  for (int mt = 0; mt < 2; ++mt)
#pragma unroll
    for (int i = 0; i < 4; ++i) {
      int row = rw + 16 * mt + kg * 4 + i;
      int ng = n0 + row;
      if (ng < NN) {
#pragma unroll
        for (int nt = 0; nt < 8; ++nt) {
          float o = (acc[mt][nt][i] - lmean[mt][i]) * lrstd[mt][i] * sv[nt] + ov[nt];
          size_t idx = (size_t)ng * LDIM + nt * 16 + lr;
          float nv = nodes_f[idx] + o;
          nodes_f[idx] = nv;
          nodes_bf[idx] = f2bf(nv);
        }
      }
    }
}

// ---- decoder: 128->128->128->3 (no LN) ----
__global__ __launch_bounds__(256, 2)
void k_dec_m(const ushort_t* __restrict__ nodes_bf,
             const ushort_t* __restrict__ Wt0, const float* __restrict__ b0,
             const ushort_t* __restrict__ Wt1, const float* __restrict__ b1,
             const float* __restrict__ W2f, const float* __restrict__ b2,
             float* __restrict__ out) {
  __shared__ ushort_t Abuf[128 * PADB];
  __shared__ ushort_t Wbuf[128 * PADB];
  const int t = threadIdx.x;
  const int lane = t & 63, wid = t >> 6;
  const int lr = lane & 15, kg = lane >> 4;
  const int rw = wid * 32;
  const int n0 = blockIdx.x * 128;

  {
    const int r = t >> 1, h = t & 1;
    const int ng = n0 + r;
    ushort_t* dst = &Abuf[r * PADB + h * 64];
    if (ng < NN) {
      const ushort_t* src = nodes_bf + (size_t)ng * LDIM + h * 64;
#pragma unroll
      for (int q = 0; q < 8; ++q)
        *(uint4*)(dst + q * 8) = *(const uint4*)(src + q * 8);
    } else {
      uint4 z; z.x = z.y = z.z = z.w = 0u;
#pragma unroll
      for (int q = 0; q < 8; ++q) *(uint4*)(dst + q * 8) = z;
    }
  }
  f32x4 acc[2][8];
  INIT_ACC(b0)
  STAGE_WT(Wt0, 128, 0)
  __syncthreads();
  MFMA_K128()
  __syncthreads();
  RELU_TO_ABUF()
  INIT_ACC(b1)
  STAGE_WT(Wt1, 128, 0)
  __syncthreads();
  MFMA_K128()
  __syncthreads();
  RELU_TO_ABUF()
  __syncthreads();

  if (t < 128) {
    const int ng = n0 + t;
    if (ng < NN) {
      float s0 = b2[0], s1 = b2[1], s2 = b2[2];
      for (int k = 0; k < 128; ++k) {
        float xv = bf2f(Abuf[t * PADB + k]);
        s0 = fmaf(xv, W2f[k * 3 + 0], s0);
        s1 = fmaf(xv, W2f[k * 3 + 1], s1);
        s2 = fmaf(xv, W2f[k * 3 + 2], s2);
      }
      out[(size_t)ng * 3 + 0] = s0;
      out[(size_t)ng * 3 + 1] = s1;
      out[(size_t)ng * 3 + 2] = s2;
    }
  }
}

extern "C" void kernel_launch(void* const* d_in, const int* in_sizes, int n_in,
                              void* d_out, int out_size, void* d_ws, size_t ws_size,
                              hipStream_t stream) {
  const float* vel_hist = (const float*)d_in[0];
  const float* vel_mag  = (const float*)d_in[1];
  const float* bnd      = (const float*)d_in[2];
  const float* force    = (const float*)d_in[3];
  const float* rel_disp = (const float*)d_in[4];
  const float* rel_dist = (const float*)d_in[5];
  const int*   senders   = (const int*)d_in[6];
  const int*   receivers = (const int*)d_in[7];
  const float* en_W0 = (const float*)d_in[8];  const float* en_b0 = (const float*)d_in[9];
  const float* en_W1 = (const float*)d_in[10]; const float* en_b1 = (const float*)d_in[11];
  const float* en_W2 = (const float*)d_in[12]; const float* en_b2 = (const float*)d_in[13];
  const float* ee_W0 = (const float*)d_in[14]; const float* ee_b0 = (const float*)d_in[15];
  const float* ee_W1 = (const float*)d_in[16]; const float* ee_b1 = (const float*)d_in[17];
  const float* ee_W2 = (const float*)d_in[18]; const float* ee_b2 = (const float*)d_in[19];
  const float* pe_W0 = (const float*)d_in[20]; const float* pe_b0 = (const float*)d_in[21];
  const float* pe_W1 = (const float*)d_in[22]; const float* pe_b1 = (const float*)d_in[23];
  const float* pe_W2 = (const float*)d_in[24]; const float* pe_b2 = (const float*)d_in[25];
  const float* pn_W0 = (const float*)d_in[26]; const float* pn_b0 = (const float*)d_in[27];
  const float* pn_W1 = (const float*)d_in[28]; const float* pn_b1 = (const float*)d_in[29];
  const float* pn_W2 = (const float*)d_in[30]; const float* pn_b2 = (const float*)d_in[31];
  const float* de_W0 = (const float*)d_in[32]; const float* de_b0 = (const float*)d_in[33];
  const float* de_W1 = (const float*)d_in[34]; const float* de_b1 = (const float*)d_in[35];
  const float* de_W2 = (const float*)d_in[36]; const float* de_b2 = (const float*)d_in[37];
  const float* en_s = (const float*)d_in[38]; const float* en_o = (const float*)d_in[39];
  const float* ee_s = (const float*)d_in[40]; const float* ee_o = (const float*)d_in[41];
  const float* pe_s = (const float*)d_in[42]; const float* pe_o = (const float*)d_in[43];
  const float* pn_s = (const float*)d_in[44]; const float* pn_o = (const float*)d_in[45];

  // ---- workspace layout ----
  float* nodes_f = (float*)d_ws;                               // NN*128 f32
  float* edges_f = nodes_f + (size_t)NN * LDIM;                // NE*128 f32
  ushort_t* nodes_bf = (ushort_t*)(edges_f + (size_t)NE * LDIM);
  ushort_t* aggr_bf  = nodes_bf + (size_t)NN * LDIM;
  ushort_t* enew     = aggr_bf + (size_t)NN * LDIM;            // NE*128 bf16
  ushort_t* w = enew + (size_t)NE * LDIM;
  ushort_t* wEn0 = w; w += 128 * 32;
  ushort_t* wEn1 = w; w += 128 * 128;
  ushort_t* wEn2 = w; w += 128 * 128;
  ushort_t* wEe0 = w; w += 128 * 32;
  ushort_t* wEe1 = w; w += 128 * 128;
  ushort_t* wEe2 = w; w += 128 * 128;
  ushort_t* wPe0 = w; w += (size_t)NSTEP * 128 * 384;
  ushort_t* wPe1 = w; w += (size_t)NSTEP * 128 * 128;
  ushort_t* wPe2 = w; w += (size_t)NSTEP * 128 * 128;
  ushort_t* wPn0 = w; w += (size_t)NSTEP * 128 * 256;
  ushort_t* wPn1 = w; w += (size_t)NSTEP * 128 * 128;
  ushort_t* wPn2 = w; w += (size_t)NSTEP * 128 * 128;
  ushort_t* wDe0 = w; w += 128 * 128;
  ushort_t* wDe1 = w; w += 128 * 128;
  int* cnt       = (int*)w;
  int* row_start = cnt + NN;          // NN+1
  int* cursor    = row_start + NN + 1;
  int* esrc      = cursor + NN;
  int* sSend     = esrc + NE;
  int* sRecv     = sSend + NE;

  auto prep = [&](const float* src, ushort_t* dst, int Ks, int Kd, int N_, int st) {
    size_t total = (size_t)st * N_ * Kd;
    int blocks = (int)((total + 255) / 256);
    if (blocks > 1024) blocks = 1024;
    k_prep_w<<<blocks, 256, 0, stream>>>(src, dst, Ks, Kd, N_, st);
  };
  prep(en_W0, wEn0, 29, 32, 128, 1);
  prep(en_W1, wEn1, 128, 128, 128, 1);
  prep(en_W2, wEn2, 128, 128, 128, 1);
  prep(ee_W0, wEe0, 4, 32, 128, 1);
  prep(ee_W1, wEe1, 128, 128, 128, 1);
  prep(ee_W2, wEe2, 128, 128, 128, 1);
  prep(pe_W0, wPe0, 384, 384, 128, NSTEP);
  prep(pe_W1, wPe1, 128, 128, 128, NSTEP);
  prep(pe_W2, wPe2, 128, 128, 128, NSTEP);
  prep(pn_W0, wPn0, 256, 256, 128, NSTEP);
  prep(pn_W1, wPn1, 128, 128, 128, NSTEP);
  prep(pn_W2, wPn2, 128, 128, 128, NSTEP);
  prep(de_W0, wDe0, 128, 128, 128, 1);
  prep(de_W1, wDe1, 128, 128, 128, 1);

  // ---- counting sort by receiver ----
  hipMemsetAsync(cnt, 0, NN * sizeof(int), stream);
  hipMemsetAsync(cursor, 0, NN * sizeof(int), stream);
  k_hist<<<(NE + 255) / 256, 256, 0, stream>>>(receivers, cnt);
  k_scan<<<1, 256, 0, stream>>>(cnt, row_start);
  k_scatter<<<(NE + 255) / 256, 256, 0, stream>>>(senders, receivers, row_start,
                                                  cursor, esrc, sSend, sRecv);

  const int NB = (NN + 127) / 128;   // 79
  const int EB = (NE + 127) / 128;   // 1563

  k_enc_node_m<<<NB, 256, 0, stream>>>(vel_hist, vel_mag, bnd, force,
      wEn0, en_b0, wEn1, en_b1, wEn2, en_b2, en_s, en_o, nodes_f, nodes_bf);
  k_enc_edge_m<<<EB, 256, 0, stream>>>(rel_disp, rel_dist, esrc,
      wEe0, ee_b0, wEe1, ee_b1, wEe2, ee_b2, ee_s, ee_o, edges_f);

  for (int s = 0; s < NSTEP; ++s) {
    k_proc_edge_m<<<EB, 256, 0, stream>>>(nodes_bf, edges_f, enew, sSend, sRecv,
        wPe0 + (size_t)s * 128 * 384, pe_b0 + (size_t)s * LDIM,
        wPe1 + (size_t)s * 128 * 128, pe_b1 + (size_t)s * LDIM,
        wPe2 + (size_t)s * 128 * 128, pe_b2 + (size_t)s * LDIM,
        pe_s + (size_t)s * LDIM, pe_o + (size_t)s * LDIM);
    k_aggr<<<(NN + 3) / 4, 256, 0, stream>>>(enew, row_start, aggr_bf);
    k_proc_node_m<<<NB, 256, 0, stream>>>(nodes_f, nodes_bf, aggr_bf,
        wPn0 + (size_t)s * 128 * 256, pn_b0 + (size_t)s * LDIM,
        wPn1 + (size_t)s * 128 * 128, pn_b1 + (size_t)s * LDIM,
        wPn2 + (size_t)s * 128 * 128, pn_b2 + (size_t)s * LDIM,
        pn_s + (size_t)s * LDIM, pn_o + (size_t)s * LDIM);
  }

  k_dec_m<<<NB, 256, 0, stream>>>(nodes_bf, wDe0, de_b0, wDe1, de_b1, de_W2, de_b2,
                                  (float*)d_out);
}

// Round 4
// 1750.349 us; speedup vs baseline: 8.0058x; 1.1584x over previous
//
#include <hip/hip_runtime.h>

#define NN 10000
#define NE 200000
#define LDIM 128
#define PADB 136   // bf16 elements per LDS row (128 + 8)
#define NSTEP 10
#define LN_EPS 1e-5f

typedef unsigned short ushort_t;
typedef __attribute__((ext_vector_type(8))) short short8;
typedef __attribute__((ext_vector_type(4))) float f32x4;

#define MFMA16(a, b, c) __builtin_amdgcn_mfma_f32_16x16x32_bf16(a, b, c, 0, 0, 0)

__device__ __forceinline__ ushort_t f2bf(float f) {
  unsigned int u = __float_as_uint(f);
  return (ushort_t)((u + 0x7FFFu + ((u >> 16) & 1u)) >> 16);
}
__device__ __forceinline__ float bf2f(ushort_t h) {
  return __uint_as_float(((unsigned int)h) << 16);
}

// ---- shared-macro context: kernels declare t, lr, kg, rw, Abuf, Wbuf, acc ----

#define STAGE_WT(WT, KTOT, K0)                                              \
  {                                                                         \
    const ushort_t* src_ = (WT) + (size_t)(t >> 1) * (KTOT) + (K0) + (t & 1) * 64; \
    ushort_t* dst_ = &Wbuf[(t >> 1) * PADB + (t & 1) * 64];                 \
    _Pragma("unroll")                                                       \
    for (int q_ = 0; q_ < 8; ++q_)                                          \
      *(uint4*)(dst_ + q_ * 8) = *(const uint4*)(src_ + q_ * 8);            \
  }

#define INIT_ACC(BG)                                                        \
  _Pragma("unroll")                                                         \
  for (int nt_ = 0; nt_ < 8; ++nt_) {                                       \
    float bv_ = (BG)[nt_ * 16 + lr];                                        \
    acc[0][nt_] = (f32x4){bv_, bv_, bv_, bv_};                              \
    acc[1][nt_] = acc[0][nt_];                                              \
  }

#define MFMA_K128()                                                         \
  _Pragma("unroll")                                                         \
  for (int ks_ = 0; ks_ < 4; ++ks_) {                                       \
    short8 a0_ = *(const short8*)&Abuf[(rw + lr) * PADB + ks_ * 32 + kg * 8];        \
    short8 a1_ = *(const short8*)&Abuf[(rw + 16 + lr) * PADB + ks_ * 32 + kg * 8];   \
    _Pragma("unroll")                                                       \
    for (int nt_ = 0; nt_ < 8; ++nt_) {                                     \
      short8 b_ = *(const short8*)&Wbuf[(nt_ * 16 + lr) * PADB + ks_ * 32 + kg * 8]; \
      acc[0][nt_] = MFMA16(a0_, b_, acc[0][nt_]);                           \
      acc[1][nt_] = MFMA16(a1_, b_, acc[1][nt_]);                           \
    }                                                                       \
  }

#define RELU_TO_ABUF()                                                      \
  _Pragma("unroll")                                                         \
  for (int mt_ = 0; mt_ < 2; ++mt_) {                                       \
    _Pragma("unroll")                                                       \
    for (int nt_ = 0; nt_ < 8; ++nt_) {                                     \
      _Pragma("unroll")                                                     \
      for (int i_ = 0; i_ < 4; ++i_) {                                      \
        int row_ = rw + 16 * mt_ + kg * 4 + i_;                             \
        Abuf[row_ * PADB + nt_ * 16 + lr] = f2bf(fmaxf(acc[mt_][nt_][i_], 0.f)); \
      }                                                                     \
    }                                                                       \
  }

#define LN_STATS2(MARR, RARR)                                               \
  float MARR[2][4], RARR[2][4];                                             \
  _Pragma("unroll")                                                         \
  for (int mt_ = 0; mt_ < 2; ++mt_) {                                       \
    _Pragma("unroll")                                                       \
    for (int i_ = 0; i_ < 4; ++i_) {                                        \
      float s_ = 0.f;                                                       \
      _Pragma("unroll")                                                     \
      for (int nt_ = 0; nt_ < 8; ++nt_) s_ += acc[mt_][nt_][i_];            \
      s_ += __shfl_xor(s_, 1); s_ += __shfl_xor(s_, 2);                     \
      s_ += __shfl_xor(s_, 4); s_ += __shfl_xor(s_, 8);                     \
      float m_ = s_ * (1.f / 128.f);                                        \
      float v_ = 0.f;                                                       \
      _Pragma("unroll")                                                     \
      for (int nt_ = 0; nt_ < 8; ++nt_) {                                   \
        float d_ = acc[mt_][nt_][i_] - m_; v_ = fmaf(d_, d_, v_);           \
      }                                                                     \
      v_ += __shfl_xor(v_, 1); v_ += __shfl_xor(v_, 2);                     \
      v_ += __shfl_xor(v_, 4); v_ += __shfl_xor(v_, 8);                     \
      MARR[mt_][i_] = m_;                                                   \
      RARR[mt_][i_] = rsqrtf(v_ * (1.f / 128.f) + LN_EPS);                  \
    }                                                                       \
  }

// write LN'd outputs to fp32 LDS buffer (stride 132), fragment layout -> row layout
#define LN_TO_FBUF(FB)                                                      \
  _Pragma("unroll")                                                         \
  for (int mt_ = 0; mt_ < 2; ++mt_)                                         \
    _Pragma("unroll")                                                       \
    for (int i_ = 0; i_ < 4; ++i_) {                                        \
      int row_ = rw + 16 * mt_ + kg * 4 + i_;                               \
      _Pragma("unroll")                                                     \
      for (int nt_ = 0; nt_ < 8; ++nt_)                                     \
        (FB)[row_ * 132 + nt_ * 16 + lr] =                                  \
            (acc[mt_][nt_][i_] - lmean[mt_][i_]) * lrstd[mt_][i_] * sv[nt_] + ov[nt_]; \
    }

// ---- weight prep: fp32 [steps][Ksrc][N] -> bf16 [steps][N][Kdst] ----
__global__ void k_prep_w(const float* __restrict__ src, ushort_t* __restrict__ dst,
                         int Ksrc, int Kdst, int N, int steps) {
  const size_t total = (size_t)steps * N * Kdst;
  for (size_t idx = (size_t)blockIdx.x * blockDim.x + threadIdx.x; idx < total;
       idx += (size_t)gridDim.x * blockDim.x) {
    int k = (int)(idx % Kdst);
    size_t tmp = idx / Kdst;
    int n = (int)(tmp % N);
    int s = (int)(tmp / N);
    float v = (k < Ksrc) ? src[((size_t)s * Ksrc + k) * N + n] : 0.f;
    dst[idx] = f2bf(v);
  }
}

// ---- counting sort of edges by receiver ----
__global__ void k_hist(const int* __restrict__ recv, int* __restrict__ cnt) {
  int e = blockIdx.x * 256 + threadIdx.x;
  if (e < NE) atomicAdd(&cnt[recv[e]], 1);
}

__global__ __launch_bounds__(256)
void k_scan(const int* __restrict__ cnt, int* __restrict__ row_start) {
  __shared__ int part[256];
  const int t = threadIdx.x;
  const int base = t * 40;                 // 256*40 = 10240 >= NN
  int sum = 0;
  for (int i = 0; i < 40; ++i) {
    int b = base + i;
    if (b < NN) sum += cnt[b];
  }
  part[t] = sum;
  __syncthreads();
  for (int off = 1; off < 256; off <<= 1) {
    int v = part[t];
    int u = (t >= off) ? part[t - off] : 0;
    __syncthreads();
    part[t] = v + u;
    __syncthreads();
  }
  int run = (t == 0) ? 0 : part[t - 1];
  for (int i = 0; i < 40; ++i) {
    int b = base + i;
    if (b < NN) { row_start[b] = run; run += cnt[b]; }
  }
  if (t == 255) row_start[NN] = run;       // == NE
}

__global__ void k_scatter(const int* __restrict__ send, const int* __restrict__ recv,
                          const int* __restrict__ row_start, int* __restrict__ cursor,
                          int* __restrict__ esrc, int* __restrict__ sSend,
                          int* __restrict__ sRecv) {
  int e = blockIdx.x * 256 + threadIdx.x;
  if (e >= NE) return;
  int r = recv[e];
  int pos = row_start[r] + atomicAdd(&cursor[r], 1);
  esrc[pos] = e;
  sSend[pos] = send[e];
  sRecv[pos] = r;
}

// ---- node encoder: concat(29)->128->128->128, LN ----
__global__ __launch_bounds__(256, 2)
void k_enc_node_m(const float* __restrict__ vh, const float* __restrict__ vm,
                  const float* __restrict__ bd, const float* __restrict__ fc,
                  const ushort_t* __restrict__ Wt0, const float* __restrict__ b0,
                  const ushort_t* __restrict__ Wt1, const float* __restrict__ b1,
                  const ushort_t* __restrict__ Wt2, const float* __restrict__ b2,
                  const float* __restrict__ lns, const float* __restrict__ lno,
                  float* __restrict__ nodes_f, ushort_t* __restrict__ nodes_bf) {
  __shared__ ushort_t Abuf[128 * PADB];
  __shared__ ushort_t Wbuf[128 * PADB];
  const int t = threadIdx.x;
  const int lane = t & 63, wid = t >> 6;
  const int lr = lane & 15, kg = lane >> 4;
  const int rw = wid * 32;
  const int n0 = blockIdx.x * 128;

  for (int idx = t; idx < 128 * 32; idx += 256) {
    int r = idx >> 5, k = idx & 31;
    int ng = n0 + r;
    float v = 0.f;
    if (ng < NN) {
      if (k < 15)      v = vh[(size_t)ng * 15 + k];
      else if (k < 20) v = vm[(size_t)ng * 5 + (k - 15)];
      else if (k < 26) v = bd[(size_t)ng * 6 + (k - 20)];
      else if (k < 29) v = fc[(size_t)ng * 3 + (k - 26)];
    }
    Abuf[r * PADB + k] = f2bf(v);
  }
  {
    const ushort_t* src = Wt0 + (t >> 1) * 32 + (t & 1) * 16;
    ushort_t* dst = &Wbuf[(t >> 1) * PADB + (t & 1) * 16];
    *(uint4*)dst = *(const uint4*)src;
    *(uint4*)(dst + 8) = *(const uint4*)(src + 8);
  }
  f32x4 acc[2][8];
  INIT_ACC(b0)
  __syncthreads();
  {
    short8 a0_ = *(const short8*)&Abuf[(rw + lr) * PADB + kg * 8];
    short8 a1_ = *(const short8*)&Abuf[(rw + 16 + lr) * PADB + kg * 8];
#pragma unroll
    for (int nt_ = 0; nt_ < 8; ++nt_) {
      short8 b_ = *(const short8*)&Wbuf[(nt_ * 16 + lr) * PADB + kg * 8];
      acc[0][nt_] = MFMA16(a0_, b_, acc[0][nt_]);
      acc[1][nt_] = MFMA16(a1_, b_, acc[1][nt_]);
    }
  }
  __syncthreads();
  RELU_TO_ABUF()
  INIT_ACC(b1)
  STAGE_WT(Wt1, 128, 0)
  __syncthreads();
  MFMA_K128()
  __syncthreads();
  RELU_TO_ABUF()
  INIT_ACC(b2)
  STAGE_WT(Wt2, 128, 0)
  __syncthreads();
  MFMA_K128()

  LN_STATS2(lmean, lrstd)
  float sv[8], ov[8];
#pragma unroll
  for (int nt = 0; nt < 8; ++nt) { sv[nt] = lns[nt * 16 + lr]; ov[nt] = lno[nt * 16 + lr]; }
#pragma unroll
  for (int mt = 0; mt < 2; ++mt)
#pragma unroll
    for (int i = 0; i < 4; ++i) {
      int row = rw + 16 * mt + kg * 4 + i;
      int ng = n0 + row;
      if (ng < NN) {
#pragma unroll
        for (int nt = 0; nt < 8; ++nt) {
          float o = (acc[mt][nt][i] - lmean[mt][i]) * lrstd[mt][i] * sv[nt] + ov[nt];
          size_t idx = (size_t)ng * LDIM + nt * 16 + lr;
          nodes_f[idx] = o;
          nodes_bf[idx] = f2bf(o);
        }
      }
    }
}

// ---- edge encoder (sorted order, gathers via esrc); flat contiguous store ----
__global__ __launch_bounds__(256, 2)
void k_enc_edge_m(const float* __restrict__ rel_disp, const float* __restrict__ rel_dist,
                  const int* __restrict__ esrc,
                  const ushort_t* __restrict__ Wt0, const float* __restrict__ b0,
                  const ushort_t* __restrict__ Wt1, const float* __restrict__ b1,
                  const ushort_t* __restrict__ Wt2, const float* __restrict__ b2,
                  const float* __restrict__ lns, const float* __restrict__ lno,
                  float* __restrict__ edges_f) {
  __shared__ ushort_t smem[2 * 128 * PADB];
  __shared__ int eidx[128];
  ushort_t* Abuf = smem;
  ushort_t* Wbuf = smem + 128 * PADB;
  const int t = threadIdx.x;
  const int lane = t & 63, wid = t >> 6;
  const int lr = lane & 15, kg = lane >> 4;
  const int rw = wid * 32;
  const int e0 = blockIdx.x * 128;

  if (t < 128) eidx[t] = (e0 + t < NE) ? esrc[e0 + t] : 0;
  __syncthreads();

  for (int idx = t; idx < 128 * 32; idx += 256) {
    int r = idx >> 5, k = idx & 31;
    float v = 0.f;
    if (e0 + r < NE) {
      int eo = eidx[r];
      if (k < 3)       v = rel_disp[(size_t)eo * 3 + k];
      else if (k == 3) v = rel_dist[eo];
    }
    Abuf[r * PADB + k] = f2bf(v);
  }
  {
    const ushort_t* src = Wt0 + (t >> 1) * 32 + (t & 1) * 16;
    ushort_t* dst = &Wbuf[(t >> 1) * PADB + (t & 1) * 16];
    *(uint4*)dst = *(const uint4*)src;
    *(uint4*)(dst + 8) = *(const uint4*)(src + 8);
  }
  f32x4 acc[2][8];
  INIT_ACC(b0)
  __syncthreads();
  {
    short8 a0_ = *(const short8*)&Abuf[(rw + lr) * PADB + kg * 8];
    short8 a1_ = *(const short8*)&Abuf[(rw + 16 + lr) * PADB + kg * 8];
#pragma unroll
    for (int nt_ = 0; nt_ < 8; ++nt_) {
      short8 b_ = *(const short8*)&Wbuf[(nt_ * 16 + lr) * PADB + kg * 8];
      acc[0][nt_] = MFMA16(a0_, b_, acc[0][nt_]);
      acc[1][nt_] = MFMA16(a1_, b_, acc[1][nt_]);
    }
  }
  __syncthreads();
  RELU_TO_ABUF()
  INIT_ACC(b1)
  STAGE_WT(Wt1, 128, 0)
  __syncthreads();
  MFMA_K128()
  __syncthreads();
  RELU_TO_ABUF()
  INIT_ACC(b2)
  STAGE_WT(Wt2, 128, 0)
  __syncthreads();
  MFMA_K128()

  LN_STATS2(lmean, lrstd)
  float sv[8], ov[8];
#pragma unroll
  for (int nt = 0; nt < 8; ++nt) { sv[nt] = lns[nt * 16 + lr]; ov[nt] = lno[nt * 16 + lr]; }

  float* fbuf = (float*)smem;
  __syncthreads();                 // all MFMA LDS reads done
  LN_TO_FBUF(fbuf)
  __syncthreads();
  // flat contiguous store: each instruction = 64 lanes x 16B = 1KB contiguous
#pragma unroll
  for (int q = 0; q < 16; ++q) {
    int F = wid * 4096 + q * 256 + lane * 4;   // float index within block tile
    int row = F >> 7, col = F & 127;
    if (e0 + row < NE) {
      float4 v = *(const float4*)&fbuf[row * 132 + col];
      *(float4*)&edges_f[(size_t)e0 * LDIM + F] = v;
    }
  }
}

// ---- processor edge block (sorted edges): MLP -> LN -> residual + fused aggr ----
__global__ __launch_bounds__(256, 2)
void k_proc_edge_m(const ushort_t* __restrict__ nodes_bf, float* __restrict__ edges_f,
                   float* __restrict__ aggr,
                   const int* __restrict__ sSend, const int* __restrict__ sRecv,
                   const ushort_t* __restrict__ Wt0, const float* __restrict__ b0,
                   const ushort_t* __restrict__ Wt1, const float* __restrict__ b1,
                   const ushort_t* __restrict__ Wt2, const float* __restrict__ b2,
                   const float* __restrict__ lns, const float* __restrict__ lno) {
  __shared__ ushort_t smem[2 * 128 * PADB];
  __shared__ int sidx[128], ridx[128];
  ushort_t* Abuf = smem;
  ushort_t* Wbuf = smem + 128 * PADB;
  const int t = threadIdx.x;
  const int lane = t & 63, wid = t >> 6;
  const int lr = lane & 15, kg = lane >> 4;
  const int rw = wid * 32;
  const int e0 = blockIdx.x * 128;

  if (t < 128) sidx[t] = (e0 + t < NE) ? sSend[e0 + t] : 0;
  else         ridx[t - 128] = (e0 + t - 128 < NE) ? sRecv[e0 + t - 128] : -1;

  f32x4 acc[2][8];
  float4 eold[16];
  INIT_ACC(b0)
  __syncthreads();

#pragma unroll
  for (int seg = 0; seg < 3; ++seg) {
    if (seg) __syncthreads();
    if (seg < 2) {
      const int r = t >> 1, h = t & 1;
      const int srow = (seg == 0) ? sidx[r] : ((ridx[r] < 0) ? 0 : ridx[r]);
      const ushort_t* src = nodes_bf + (size_t)srow * LDIM + h * 64;
      ushort_t* dst = &Abuf[r * PADB + h * 64];
#pragma unroll
      for (int q = 0; q < 8; ++q)
        *(uint4*)(dst + q * 8) = *(const uint4*)(src + q * 8);
    } else {
      // flat contiguous load of edges_f; keep fp32 in registers for residual
#pragma unroll
      for (int q = 0; q < 16; ++q) {
        int F = wid * 4096 + q * 256 + lane * 4;
        int row = F >> 7, col = F & 127;
        float4 v;
        if (e0 + row < NE) v = *(const float4*)&edges_f[(size_t)e0 * LDIM + F];
        else { v.x = v.y = v.z = v.w = 0.f; }
        eold[q] = v;
        ushort4 hv;
        hv.x = f2bf(v.x); hv.y = f2bf(v.y); hv.z = f2bf(v.z); hv.w = f2bf(v.w);
        *(ushort4*)&Abuf[row * PADB + col] = hv;
      }
    }
    STAGE_WT(Wt0, 384, seg * 128)
    __syncthreads();
    MFMA_K128()
  }
  __syncthreads();
  RELU_TO_ABUF()
  INIT_ACC(b1)
  STAGE_WT(Wt1, 128, 0)
  __syncthreads();
  MFMA_K128()
  __syncthreads();
  RELU_TO_ABUF()
  INIT_ACC(b2)
  STAGE_WT(Wt2, 128, 0)
  __syncthreads();
  MFMA_K128()

  LN_STATS2(lmean, lrstd)
  float sv[8], ov[8];
#pragma unroll
  for (int nt = 0; nt < 8; ++nt) { sv[nt] = lns[nt * 16 + lr]; ov[nt] = lno[nt * 16 + lr]; }

  float* fbuf = (float*)smem;
  __syncthreads();                 // all MFMA LDS reads done
  LN_TO_FBUF(fbuf)
  __syncthreads();

  // residual update, flat contiguous (uses eold registers; no re-read)
#pragma unroll
  for (int q = 0; q < 16; ++q) {
    int F = wid * 4096 + q * 256 + lane * 4;
    int row = F >> 7, col = F & 127;
    if (e0 + row < NE) {
      float4 nv = *(const float4*)&fbuf[row * 132 + col];
      nv.x += eold[q].x; nv.y += eold[q].y; nv.z += eold[q].z; nv.w += eold[q].w;
      *(float4*)&edges_f[(size_t)e0 * LDIM + F] = nv;
    }
  }

  // fused segment-sum aggregation: thread t owns column c over a 64-row window
  {
    const int c = t & 127;
    const int half = t >> 7;
    const int r0 = half * 64, r1 = r0 + 64;
    float run = 0.f;
    int cur = ridx[r0];
    for (int r = r0; r < r1; ++r) {
      int rid = ridx[r];
      if (rid != cur) {
        if (cur >= 0) atomicAdd(&aggr[(size_t)cur * LDIM + c], run);
        run = 0.f;
        cur = rid;
      }
      run += fbuf[r * 132 + c];
    }
    if (cur >= 0) atomicAdd(&aggr[(size_t)cur * LDIM + c], run);
  }
}

// ---- processor node block: [nd, aggr_f32](256)->MLP->LN; nd += n_new ----
__global__ __launch_bounds__(256, 2)
void k_proc_node_m(float* __restrict__ nodes_f, ushort_t* __restrict__ nodes_bf,
                   const float* __restrict__ aggr,
                   const ushort_t* __restrict__ Wt0, const float* __restrict__ b0,
                   const ushort_t* __restrict__ Wt1, const float* __restrict__ b1,
                   const ushort_t* __restrict__ Wt2, const float* __restrict__ b2,
                   const float* __restrict__ lns, const float* __restrict__ lno) {
  __shared__ ushort_t Abuf[128 * PADB];
  __shared__ ushort_t Wbuf[128 * PADB];
  const int t = threadIdx.x;
  const int lane = t & 63, wid = t >> 6;
  const int lr = lane & 15, kg = lane >> 4;
  const int rw = wid * 32;
  const int n0 = blockIdx.x * 128;

  f32x4 acc[2][8];
  INIT_ACC(b0)

#pragma unroll
  for (int seg = 0; seg < 2; ++seg) {
    if (seg) __syncthreads();
    {
      const int r = t >> 1, h = t & 1;
      const int ng = n0 + r;
      ushort_t* dst = &Abuf[r * PADB + h * 64];
      if (ng < NN) {
        if (seg == 0) {
          const ushort_t* src = nodes_bf + (size_t)ng * LDIM + h * 64;
#pragma unroll
          for (int q = 0; q < 8; ++q)
            *(uint4*)(dst + q * 8) = *(const uint4*)(src + q * 8);
        } else {
          const float* src = aggr + (size_t)ng * LDIM + h * 64;
#pragma unroll
          for (int q = 0; q < 16; ++q) {
            float4 fv = *(const float4*)(src + q * 4);
            ushort4 hv;
            hv.x = f2bf(fv.x); hv.y = f2bf(fv.y); hv.z = f2bf(fv.z); hv.w = f2bf(fv.w);
            *(ushort4*)(dst + q * 4) = hv;
          }
        }
      } else {
        uint4 z; z.x = z.y = z.z = z.w = 0u;
#pragma unroll
        for (int q = 0; q < 8; ++q) *(uint4*)(dst + q * 8) = z;
      }
    }
    STAGE_WT(Wt0, 256, seg * 128)
    __syncthreads();
    MFMA_K128()
  }
  __syncthreads();
  RELU_TO_ABUF()
  INIT_ACC(b1)
  STAGE_WT(Wt1, 128, 0)
  __syncthreads();
  MFMA_K128()
  __syncthreads();
  RELU_TO_ABUF()
  INIT_ACC(b2)
  STAGE_WT(Wt2, 128, 0)
  __syncthreads();
  MFMA_K128()

  LN_STATS2(lmean, lrstd)
  float sv[8], ov[8];
#pragma unroll
  for (int nt = 0; nt < 8; ++nt) { sv[nt] = lns[nt * 16 + lr]; ov[nt] = lno[nt * 16 + lr]; }
#pragma unroll
  for (int mt = 0; mt < 2; ++mt)
#pragma unroll
    for (int i = 0; i < 4; ++i) {
      int row = rw + 16 * mt + kg * 4 + i;
      int ng = n0 + row;
      if (ng < NN) {
#pragma unroll
        for (int nt = 0; nt < 8; ++nt) {
          float o = (acc[mt][nt][i] - lmean[mt][i]) * lrstd[mt][i] * sv[nt] + ov[nt];
          size_t idx = (size_t)ng * LDIM + nt * 16 + lr;
          float nv = nodes_f[idx] + o;
          nodes_f[idx] = nv;
          nodes_bf[idx] = f2bf(nv);
        }
      }
    }
}

// ---- decoder: 128->128->128->3 (no LN) ----
__global__ __launch_bounds__(256, 2)
void k_dec_m(const ushort_t* __restrict__ nodes_bf,
             const ushort_t* __restrict__ Wt0, const float* __restrict__ b0,
             const ushort_t* __restrict__ Wt1, const float* __restrict__ b1,
             const float* __restrict__ W2f, const float* __restrict__ b2,
             float* __restrict__ out) {
  __shared__ ushort_t Abuf[128 * PADB];
  __shared__ ushort_t Wbuf[128 * PADB];
  const int t = threadIdx.x;
  const int lane = t & 63, wid = t >> 6;
  const int lr = lane & 15, kg = lane >> 4;
  const int rw = wid * 32;
  const int n0 = blockIdx.x * 128;

  {
    const int r = t >> 1, h = t & 1;
    const int ng = n0 + r;
    ushort_t* dst = &Abuf[r * PADB + h * 64];
    if (ng < NN) {
      const ushort_t* src = nodes_bf + (size_t)ng * LDIM + h * 64;
#pragma unroll
      for (int q = 0; q < 8; ++q)
        *(uint4*)(dst + q * 8) = *(const uint4*)(src + q * 8);
    } else {
      uint4 z; z.x = z.y = z.z = z.w = 0u;
#pragma unroll
      for (int q = 0; q < 8; ++q) *(uint4*)(dst + q * 8) = z;
    }
  }
  f32x4 acc[2][8];
  INIT_ACC(b0)
  STAGE_WT(Wt0, 128, 0)
  __syncthreads();
  MFMA_K128()
  __syncthreads();
  RELU_TO_ABUF()
  INIT_ACC(b1)
  STAGE_WT(Wt1, 128, 0)
  __syncthreads();
  MFMA_K128()
  __syncthreads();
  RELU_TO_ABUF()
  __syncthreads();

  if (t < 128) {
    const int ng = n0 + t;
    if (ng < NN) {
      float s0 = b2[0], s1 = b2[1], s2 = b2[2];
      for (int k = 0; k < 128; ++k) {
        float xv = bf2f(Abuf[t * PADB + k]);
        s0 = fmaf(xv, W2f[k * 3 + 0], s0);
        s1 = fmaf(xv, W2f[k * 3 + 1], s1);
        s2 = fmaf(xv, W2f[k * 3 + 2], s2);
      }
      out[(size_t)ng * 3 + 0] = s0;
      out[(size_t)ng * 3 + 1] = s1;
      out[(size_t)ng * 3 + 2] = s2;
    }
  }
}

extern "C" void kernel_launch(void* const* d_in, const int* in_sizes, int n_in,
                              void* d_out, int out_size, void* d_ws, size_t ws_size,
                              hipStream_t stream) {
  const float* vel_hist = (const float*)d_in[0];
  const float* vel_mag  = (const float*)d_in[1];
  const float* bnd      = (const float*)d_in[2];
  const float* force    = (const float*)d_in[3];
  const float* rel_disp = (const float*)d_in[4];
  const float* rel_dist = (const float*)d_in[5];
  const int*   senders   = (const int*)d_in[6];
  const int*   receivers = (const int*)d_in[7];
  const float* en_W0 = (const float*)d_in[8];  const float* en_b0 = (const float*)d_in[9];
  const float* en_W1 = (const float*)d_in[10]; const float* en_b1 = (const float*)d_in[11];
  const float* en_W2 = (const float*)d_in[12]; const float* en_b2 = (const float*)d_in[13];
  const float* ee_W0 = (const float*)d_in[14]; const float* ee_b0 = (const float*)d_in[15];
  const float* ee_W1 = (const float*)d_in[16]; const float* ee_b1 = (const float*)d_in[17];
  const float* ee_W2 = (const float*)d_in[18]; const float* ee_b2 = (const float*)d_in[19];
  const float* pe_W0 = (const float*)d_in[20]; const float* pe_b0 = (const float*)d_in[21];
  const float* pe_W1 = (const float*)d_in[22]; const float* pe_b1 = (const float*)d_in[23];
  const float* pe_W2 = (const float*)d_in[24]; const float* pe_b2 = (const float*)d_in[25];
  const float* pn_W0 = (const float*)d_in[26]; const float* pn_b0 = (const float*)d_in[27];
  const float* pn_W1 = (const float*)d_in[28]; const float* pn_b1 = (const float*)d_in[29];
  const float* pn_W2 = (const float*)d_in[30]; const float* pn_b2 = (const float*)d_in[31];
  const float* de_W0 = (const float*)d_in[32]; const float* de_b0 = (const float*)d_in[33];
  const float* de_W1 = (const float*)d_in[34]; const float* de_b1 = (const float*)d_in[35];
  const float* de_W2 = (const float*)d_in[36]; const float* de_b2 = (const float*)d_in[37];
  const float* en_s = (const float*)d_in[38]; const float* en_o = (const float*)d_in[39];
  const float* ee_s = (const float*)d_in[40]; const float* ee_o = (const float*)d_in[41];
  const float* pe_s = (const float*)d_in[42]; const float* pe_o = (const float*)d_in[43];
  const float* pn_s = (const float*)d_in[44]; const float* pn_o = (const float*)d_in[45];

  // ---- workspace layout ----
  float* nodes_f = (float*)d_ws;                               // NN*128 f32
  float* edges_f = nodes_f + (size_t)NN * LDIM;                // NE*128 f32
  float* aggr    = edges_f + (size_t)NE * LDIM;                // NN*128 f32
  ushort_t* nodes_bf = (ushort_t*)(aggr + (size_t)NN * LDIM);
  ushort_t* w = nodes_bf + (size_t)NN * LDIM;
  ushort_t* wEn0 = w; w += 128 * 32;
  ushort_t* wEn1 = w; w += 128 * 128;
  ushort_t* wEn2 = w; w += 128 * 128;
  ushort_t* wEe0 = w; w += 128 * 32;
  ushort_t* wEe1 = w; w += 128 * 128;
  ushort_t* wEe2 = w; w += 128 * 128;
  ushort_t* wPe0 = w; w += (size_t)NSTEP * 128 * 384;
  ushort_t* wPe1 = w; w += (size_t)NSTEP * 128 * 128;
  ushort_t* wPe2 = w; w += (size_t)NSTEP * 128 * 128;
  ushort_t* wPn0 = w; w += (size_t)NSTEP * 128 * 256;
  ushort_t* wPn1 = w; w += (size_t)NSTEP * 128 * 128;
  ushort_t* wPn2 = w; w += (size_t)NSTEP * 128 * 128;
  ushort_t* wDe0 = w; w += 128 * 128;
  ushort_t* wDe1 = w; w += 128 * 128;
  int* cnt       = (int*)w;
  int* row_start = cnt + NN;          // NN+1
  int* cursor    = row_start + NN + 1;
  int* esrc      = cursor + NN;
  int* sSend     = esrc + NE;
  int* sRecv     = sSend + NE;

  auto prep = [&](const float* src, ushort_t* dst, int Ks, int Kd, int N_, int st) {
    size_t total = (size_t)st * N_ * Kd;
    int blocks = (int)((total + 255) / 256);
    if (blocks > 1024) blocks = 1024;
    k_prep_w<<<blocks, 256, 0, stream>>>(src, dst, Ks, Kd, N_, st);
  };
  prep(en_W0, wEn0, 29, 32, 128, 1);
  prep(en_W1, wEn1, 128, 128, 128, 1);
  prep(en_W2, wEn2, 128, 128, 128, 1);
  prep(ee_W0, wEe0, 4, 32, 128, 1);
  prep(ee_W1, wEe1, 128, 128, 128, 1);
  prep(ee_W2, wEe2, 128, 128, 128, 1);
  prep(pe_W0, wPe0, 384, 384, 128, NSTEP);
  prep(pe_W1, wPe1, 128, 128, 128, NSTEP);
  prep(pe_W2, wPe2, 128, 128, 128, NSTEP);
  prep(pn_W0, wPn0, 256, 256, 128, NSTEP);
  prep(pn_W1, wPn1, 128, 128, 128, NSTEP);
  prep(pn_W2, wPn2, 128, 128, 128, NSTEP);
  prep(de_W0, wDe0, 128, 128, 128, 1);
  prep(de_W1, wDe1, 128, 128, 128, 1);

  // ---- counting sort by receiver ----
  hipMemsetAsync(cnt, 0, NN * sizeof(int), stream);
  hipMemsetAsync(cursor, 0, NN * sizeof(int), stream);
  k_hist<<<(NE + 255) / 256, 256, 0, stream>>>(receivers, cnt);
  k_scan<<<1, 256, 0, stream>>>(cnt, row_start);
  k_scatter<<<(NE + 255) / 256, 256, 0, stream>>>(senders, receivers, row_start,
                                                  cursor, esrc, sSend, sRecv);

  const int NB = (NN + 127) / 128;   // 79
  const int EB = (NE + 127) / 128;   // 1563

  k_enc_node_m<<<NB, 256, 0, stream>>>(vel_hist, vel_mag, bnd, force,
      wEn0, en_b0, wEn1, en_b1, wEn2, en_b2, en_s, en_o, nodes_f, nodes_bf);
  k_enc_edge_m<<<EB, 256, 0, stream>>>(rel_disp, rel_dist, esrc,
      wEe0, ee_b0, wEe1, ee_b1, wEe2, ee_b2, ee_s, ee_o, edges_f);

  for (int s = 0; s < NSTEP; ++s) {
    hipMemsetAsync(aggr, 0, (size_t)NN * LDIM * sizeof(float), stream);
    k_proc_edge_m<<<EB, 256, 0, stream>>>(nodes_bf, edges_f, aggr, sSend, sRecv,
        wPe0 + (size_t)s * 128 * 384, pe_b0 + (size_t)s * LDIM,
        wPe1 + (size_t)s * 128 * 128, pe_b1 + (size_t)s * LDIM,
        wPe2 + (size_t)s * 128 * 128, pe_b2 + (size_t)s * LDIM,
        pe_s + (size_t)s * LDIM, pe_o + (size_t)s * LDIM);
    k_proc_node_m<<<NB, 256, 0, stream>>>(nodes_f, nodes_bf, aggr,
        wPn0 + (size_t)s * 128 * 256, pn_b0 + (size_t)s * LDIM,
        wPn1 + (size_t)s * 128 * 128, pn_b1 + (size_t)s * LDIM,
        wPn2 + (size_t)s * 128 * 128, pn_b2 + (size_t)s * LDIM,
        pn_s + (size_t)s * LDIM, pn_o + (size_t)s * LDIM);
  }

  k_dec_m<<<NB, 256, 0, stream>>>(nodes_bf, wDe0, de_b0, wDe1, de_b1, de_W2, de_b2,
                                  (float*)d_out);
}